// Round 1
// baseline (4005.373 us; speedup 1.0000x reference)
//
#include <hip/hip_runtime.h>

#define N_ROWS 32768
#define DIM    512
#define KCB    8192

#define TM 64    // rows per block
#define TK 128   // codes per block tile
#define DC 32    // d-chunk staged in LDS

// sum of squares of one 512-wide row per 64-thread block (fixed deterministic order)
__global__ __launch_bounds__(64) void rownorm_kernel(const float* __restrict__ src,
                                                     float* __restrict__ dst) {
    const int row  = blockIdx.x;
    const int lane = threadIdx.x;
    const float* p = src + (size_t)row * DIM;
    float s = 0.0f;
#pragma unroll
    for (int i = 0; i < DIM / 64; ++i) {
        float v = p[lane + i * 64];
        s = __builtin_fmaf(v, v, s);
    }
#pragma unroll
    for (int off = 32; off > 0; off >>= 1) s += __shfl_down(s, off, 64);
    if (lane == 0) dst[row] = s;
}

// distance-GEMM + running argmin. dist = fl(fl(sumx+sume) - 2c), first-index tie-break.
__global__ __launch_bounds__(256) void argmin_kernel(const float* __restrict__ x,
                                                     const float* __restrict__ e,
                                                     const float* __restrict__ sumx,
                                                     const float* __restrict__ sume,
                                                     int* __restrict__ inds) {
    __shared__ float Xs[DC][TM];   // d-major: rows contiguous -> b128 frag reads
    __shared__ float Es[DC][TK];
    __shared__ float rb[TM][16];
    __shared__ int   rk[TM][16];

    const int tid  = threadIdx.x;
    const int tx   = tid & 15;   // 16 k-groups of 8
    const int ty   = tid >> 4;   // 16 row-groups of 4
    const int row0 = blockIdx.x * TM;

    float best[4];
    int   bestk[4];
    float sxr[4];
#pragma unroll
    for (int r = 0; r < 4; ++r) {
        best[r]  = 3.4e38f;
        bestk[r] = 0;
        sxr[r]   = sumx[row0 + ty * 4 + r];
    }

    for (int kt = 0; kt < KCB / TK; ++kt) {
        const int k0 = kt * TK;
        float acc[4][8];
#pragma unroll
        for (int r = 0; r < 4; ++r)
#pragma unroll
            for (int j = 0; j < 8; ++j) acc[r][j] = 0.0f;

        for (int c = 0; c < DIM / DC; ++c) {
            const int d0 = c * DC;
            __syncthreads();
            {   // stage X chunk: 64 rows x 32 d (transposed to d-major)
                const int row = tid >> 2;
                const int dq  = (tid & 3) * 4;
                const float* src = x + (size_t)(row0 + row) * DIM + d0 + dq;
                float4 a = *(const float4*)(src);
                float4 b = *(const float4*)(src + 16);
                Xs[dq + 0][row] = a.x;  Xs[dq + 1][row] = a.y;
                Xs[dq + 2][row] = a.z;  Xs[dq + 3][row] = a.w;
                Xs[dq + 16][row] = b.x; Xs[dq + 17][row] = b.y;
                Xs[dq + 18][row] = b.z; Xs[dq + 19][row] = b.w;
            }
            {   // stage E chunk: 128 k x 32 d (transposed to d-major)
                const int kk = tid >> 1;
                const int dq = (tid & 1) * 4;
                const float* src = e + (size_t)(k0 + kk) * DIM + d0 + dq;
                float4 a  = *(const float4*)(src);
                float4 b  = *(const float4*)(src + 8);
                float4 c4 = *(const float4*)(src + 16);
                float4 d4 = *(const float4*)(src + 24);
                Es[dq + 0][kk] = a.x;   Es[dq + 1][kk] = a.y;
                Es[dq + 2][kk] = a.z;   Es[dq + 3][kk] = a.w;
                Es[dq + 8][kk] = b.x;   Es[dq + 9][kk] = b.y;
                Es[dq + 10][kk] = b.z;  Es[dq + 11][kk] = b.w;
                Es[dq + 16][kk] = c4.x; Es[dq + 17][kk] = c4.y;
                Es[dq + 18][kk] = c4.z; Es[dq + 19][kk] = c4.w;
                Es[dq + 24][kk] = d4.x; Es[dq + 25][kk] = d4.y;
                Es[dq + 26][kk] = d4.z; Es[dq + 27][kk] = d4.w;
            }
            __syncthreads();
#pragma unroll 4
            for (int dd = 0; dd < DC; ++dd) {
                float4 xa = *(const float4*)(&Xs[dd][ty * 4]);
                float4 ea = *(const float4*)(&Es[dd][tx * 8]);
                float4 eb = *(const float4*)(&Es[dd][tx * 8 + 4]);
                float xv[4] = {xa.x, xa.y, xa.z, xa.w};
                float ev[8] = {ea.x, ea.y, ea.z, ea.w, eb.x, eb.y, eb.z, eb.w};
#pragma unroll
                for (int r = 0; r < 4; ++r)
#pragma unroll
                    for (int j = 0; j < 8; ++j)
                        acc[r][j] = __builtin_fmaf(xv[r], ev[j], acc[r][j]);
            }
        }
        // fold this k-tile into running argmin (exact reference rounding sequence)
#pragma unroll
        for (int r = 0; r < 4; ++r) {
#pragma unroll
            for (int j = 0; j < 8; ++j) {
                const int k   = k0 + tx * 8 + j;
                const float t1   = __fadd_rn(sxr[r], sume[k]);
                const float dist = __fsub_rn(t1, __fadd_rn(acc[r][j], acc[r][j]));
                // within-thread k strictly ascending -> strict < keeps first-min
                if (dist < best[r]) { best[r] = dist; bestk[r] = k; }
            }
        }
    }

    __syncthreads();
#pragma unroll
    for (int r = 0; r < 4; ++r) {
        rb[ty * 4 + r][tx] = best[r];
        rk[ty * 4 + r][tx] = bestk[r];
    }
    __syncthreads();
    if (tid < TM) {
        float bd = rb[tid][0];
        int   bk = rk[tid][0];
        for (int t = 1; t < 16; ++t) {
            float d = rb[tid][t];
            int   k = rk[tid][t];
            if (d < bd || (d == bd && k < bk)) { bd = d; bk = k; }  // np.argmin: first occurrence
        }
        inds[row0 + tid] = bk;
    }
}

// out = x + (e[ind] - x), exact elementwise fp32 replication of the STE
__global__ __launch_bounds__(256) void writeout_kernel(const float* __restrict__ x,
                                                       const float* __restrict__ e,
                                                       const int* __restrict__ inds,
                                                       float* __restrict__ out) {
    const int t  = blockIdx.x * blockDim.x + threadIdx.x;  // one float4 each
    const int n  = t >> 7;                                  // 128 float4 per row
    const int dq = (t & 127) * 4;
    const int ind = inds[n];
    const float4 xv = *(const float4*)(x + (size_t)n * DIM + dq);
    const float4 ev = *(const float4*)(e + (size_t)ind * DIM + dq);
    float4 o;
    o.x = __fadd_rn(xv.x, __fsub_rn(ev.x, xv.x));
    o.y = __fadd_rn(xv.y, __fsub_rn(ev.y, xv.y));
    o.z = __fadd_rn(xv.z, __fsub_rn(ev.z, xv.z));
    o.w = __fadd_rn(xv.w, __fsub_rn(ev.w, xv.w));
    *(float4*)(out + (size_t)n * DIM + dq) = o;
}

extern "C" void kernel_launch(void* const* d_in, const int* in_sizes, int n_in,
                              void* d_out, int out_size, void* d_ws, size_t ws_size,
                              hipStream_t stream) {
    const float* lat = (const float*)d_in[0];   // (16,2048,512) fp32
    const float* emb = (const float*)d_in[1];   // (8192,512) fp32
    float* out = (float*)d_out;

    char* ws = (char*)d_ws;
    float* sume = (float*)(ws);                                   // 8192 f
    float* sumx = (float*)(ws + (size_t)KCB * 4);                 // 32768 f
    int*   inds = (int*)  (ws + (size_t)KCB * 4 + (size_t)N_ROWS * 4);  // 32768 i

    rownorm_kernel<<<KCB, 64, 0, stream>>>(emb, sume);
    rownorm_kernel<<<N_ROWS, 64, 0, stream>>>(lat, sumx);
    argmin_kernel<<<N_ROWS / TM, 256, 0, stream>>>(lat, emb, sumx, sume, inds);
    writeout_kernel<<<(N_ROWS * DIM / 4) / 256, 256, 0, stream>>>(lat, emb, inds, out);
}

// Round 2
// 3976.487 us; speedup vs baseline: 1.0073x; 1.0073x over previous
//
#include <hip/hip_runtime.h>
#include <float.h>

#define N_ROWS 32768
#define DIM    512
#define KCB    8192

#define TM 128      // rows per block
#define TK 256      // codes per k-tile
#define DC 32       // d-chunk staged in LDS
#define NSPLIT 4    // k-range splits across blockIdx.y
#define KT_PER_SPLIT ((KCB / NSPLIT) / TK)   // 8 k-tiles per block

// sum of squares of one 512-wide row per 64-thread block (fixed deterministic order)
__global__ __launch_bounds__(64) void rownorm_kernel(const float* __restrict__ src,
                                                     float* __restrict__ dst) {
    const int row  = blockIdx.x;
    const int lane = threadIdx.x;
    const float* p = src + (size_t)row * DIM;
    float s = 0.0f;
#pragma unroll
    for (int i = 0; i < DIM / 64; ++i) {
        float v = p[lane + i * 64];
        s = __builtin_fmaf(v, v, s);
    }
#pragma unroll
    for (int off = 32; off > 0; off >>= 1) s += __shfl_down(s, off, 64);
    if (lane == 0) dst[row] = s;
}

// distance-GEMM + running argmin over one k-split.
// LDS layout (both tiles d-major, XOR-swizzled in 4-float groups):
//   X element (dd,row) at float off dd*TM + ((row>>2) ^ (dd>>2))*4 + (row&3)
//   E element (dd,k)   at float off dd*TK + ((k>>2) ^ ((k>>4)&7) ^ (dd>>2))*4 + (k&3)
// -> all staging writes and fragment reads are <=2-way bank conflicts (free).
__global__ __launch_bounds__(256, 2) void argmin_kernel(const float* __restrict__ x,
                                                        const float* __restrict__ e,
                                                        const float* __restrict__ sumx,
                                                        const float* __restrict__ sume,
                                                        float* __restrict__ cand_d,
                                                        int* __restrict__ cand_k) {
    __shared__ float Xs[DC * TM];     // 16 KB
    __shared__ float Es[DC * TK];     // 32 KB
    __shared__ float rb[TM * 16];     // 8 KB
    __shared__ int   rk[TM * 16];     // 8 KB

    const int tid  = threadIdx.x;
    const int tx   = tid & 15;    // 16 k-groups of 16 codes
    const int ty   = tid >> 4;    // 16 row-groups of 8 rows
    const int row0 = blockIdx.x * TM;
    const int ks0  = blockIdx.y * (KCB / NSPLIT);

    // loop-invariant swizzled group bases (byte-XOR distributes over <<2)
    const int xg0 = (2 * ty) * 4;
    const int xg1 = (2 * ty + 1) * 4;
    int egb[4];
#pragma unroll
    for (int h = 0; h < 4; ++h) egb[h] = ((4 * tx + h) ^ (tx & 7)) * 4;

    float sxr[8];
    float best[8];
    int   bestk[8];
#pragma unroll
    for (int r = 0; r < 8; ++r) {
        sxr[r]   = sumx[row0 + ty * 8 + r];
        best[r]  = FLT_MAX;
        bestk[r] = 0;
    }

    for (int kt = 0; kt < KT_PER_SPLIT; ++kt) {
        const int k0 = ks0 + kt * TK;
        float acc[8][16];
#pragma unroll
        for (int r = 0; r < 8; ++r)
#pragma unroll
            for (int j = 0; j < 16; ++j) acc[r][j] = 0.0f;

        for (int ch = 0; ch < DIM / DC; ++ch) {
            const int d0 = ch * DC;
            __syncthreads();
            // ---- stage X: 128 rows x 32 d, 1024 float4, 8 lanes/row (128B segs)
#pragma unroll
            for (int i = 0; i < 4; ++i) {
                const int f   = i * 256 + tid;
                const int row = f >> 3;
                const int c4  = f & 7;
                const float4 v = *(const float4*)(x + (size_t)(row0 + row) * DIM + d0 + c4 * 4);
                const int swz = (((row >> 2) ^ c4) * 4) + (row & 3);
                Xs[(4 * c4 + 0) * TM + swz] = v.x;
                Xs[(4 * c4 + 1) * TM + swz] = v.y;
                Xs[(4 * c4 + 2) * TM + swz] = v.z;
                Xs[(4 * c4 + 3) * TM + swz] = v.w;
            }
            // ---- stage E: 256 k x 32 d, 2048 float4
#pragma unroll
            for (int i = 0; i < 8; ++i) {
                const int f  = i * 256 + tid;
                const int k  = f >> 3;
                const int c4 = f & 7;
                const float4 v = *(const float4*)(e + (size_t)(k0 + k) * DIM + d0 + c4 * 4);
                const int swz = ((((k >> 2) ^ ((k >> 4) & 7)) ^ c4) * 4) + (k & 3);
                Es[(4 * c4 + 0) * TK + swz] = v.x;
                Es[(4 * c4 + 1) * TK + swz] = v.y;
                Es[(4 * c4 + 2) * TK + swz] = v.z;
                Es[(4 * c4 + 3) * TK + swz] = v.w;
            }
            __syncthreads();
            // ---- compute: 32 d-steps, 8x16 FMA microtile per thread
            for (int c8 = 0; c8 < 8; ++c8) {
                const int kshift = c8 * 4;   // swizzle key for this dd quad
#pragma unroll
                for (int u = 0; u < 4; ++u) {
                    const int dd = c8 * 4 + u;
                    const float* xr = Xs + dd * TM;
                    const float* er = Es + dd * TK;
                    const float4 xa = *(const float4*)(xr + (xg0 ^ kshift));
                    const float4 xb = *(const float4*)(xr + (xg1 ^ kshift));
                    const float4 e0 = *(const float4*)(er + (egb[0] ^ kshift));
                    const float4 e1 = *(const float4*)(er + (egb[1] ^ kshift));
                    const float4 e2 = *(const float4*)(er + (egb[2] ^ kshift));
                    const float4 e3 = *(const float4*)(er + (egb[3] ^ kshift));
                    const float xv[8]  = {xa.x, xa.y, xa.z, xa.w, xb.x, xb.y, xb.z, xb.w};
                    const float ev[16] = {e0.x, e0.y, e0.z, e0.w, e1.x, e1.y, e1.z, e1.w,
                                          e2.x, e2.y, e2.z, e2.w, e3.x, e3.y, e3.z, e3.w};
#pragma unroll
                    for (int r = 0; r < 8; ++r)
#pragma unroll
                        for (int j = 0; j < 16; ++j)
                            acc[r][j] = __builtin_fmaf(xv[r], ev[j], acc[r][j]);
                }
            }
        }
        // ---- fold k-tile into running argmin (exact reference rounding sequence)
#pragma unroll
        for (int r = 0; r < 8; ++r) {
#pragma unroll
            for (int j = 0; j < 16; ++j) {
                const int k = k0 + 16 * tx + j;   // within-thread k ascending
                const float t1   = __fadd_rn(sxr[r], sume[k]);
                const float dist = __fsub_rn(t1, __fadd_rn(acc[r][j], acc[r][j]));
                if (dist < best[r]) { best[r] = dist; bestk[r] = k; }
            }
        }
    }

    __syncthreads();
#pragma unroll
    for (int r = 0; r < 8; ++r) {
        rb[(ty * 8 + r) * 16 + tx] = best[r];
        rk[(ty * 8 + r) * 16 + tx] = bestk[r];
    }
    __syncthreads();
    if (tid < TM) {
        float bd = rb[tid * 16 + 0];
        int   bk = rk[tid * 16 + 0];
#pragma unroll
        for (int t = 1; t < 16; ++t) {
            const float d = rb[tid * 16 + t];
            const int   k = rk[tid * 16 + t];
            if (d < bd || (d == bd && k < bk)) { bd = d; bk = k; }  // first occurrence
        }
        cand_d[(size_t)(row0 + tid) * NSPLIT + blockIdx.y] = bd;
        cand_k[(size_t)(row0 + tid) * NSPLIT + blockIdx.y] = bk;
    }
}

// merge per-split candidates -> final index (first-min semantics preserved:
// splits are ascending k-ranges, ties broken by lower k)
__global__ __launch_bounds__(256) void merge_kernel(const float* __restrict__ cand_d,
                                                    const int* __restrict__ cand_k,
                                                    int* __restrict__ inds) {
    const int row = blockIdx.x * 256 + threadIdx.x;
    float bd = cand_d[(size_t)row * NSPLIT];
    int   bk = cand_k[(size_t)row * NSPLIT];
#pragma unroll
    for (int s = 1; s < NSPLIT; ++s) {
        const float d = cand_d[(size_t)row * NSPLIT + s];
        const int   k = cand_k[(size_t)row * NSPLIT + s];
        if (d < bd || (d == bd && k < bk)) { bd = d; bk = k; }
    }
    inds[row] = bk;
}

// out = x + (e[ind] - x), exact elementwise fp32 replication of the STE
__global__ __launch_bounds__(256) void writeout_kernel(const float* __restrict__ x,
                                                       const float* __restrict__ e,
                                                       const int* __restrict__ inds,
                                                       float* __restrict__ out) {
    const int t  = blockIdx.x * blockDim.x + threadIdx.x;  // one float4 each
    const int n  = t >> 7;                                  // 128 float4 per row
    const int dq = (t & 127) * 4;
    const int ind = inds[n];
    const float4 xv = *(const float4*)(x + (size_t)n * DIM + dq);
    const float4 ev = *(const float4*)(e + (size_t)ind * DIM + dq);
    float4 o;
    o.x = __fadd_rn(xv.x, __fsub_rn(ev.x, xv.x));
    o.y = __fadd_rn(xv.y, __fsub_rn(ev.y, xv.y));
    o.z = __fadd_rn(xv.z, __fsub_rn(ev.z, xv.z));
    o.w = __fadd_rn(xv.w, __fsub_rn(ev.w, xv.w));
    *(float4*)(out + (size_t)n * DIM + dq) = o;
}

extern "C" void kernel_launch(void* const* d_in, const int* in_sizes, int n_in,
                              void* d_out, int out_size, void* d_ws, size_t ws_size,
                              hipStream_t stream) {
    const float* lat = (const float*)d_in[0];   // (16,2048,512) fp32
    const float* emb = (const float*)d_in[1];   // (8192,512) fp32
    float* out = (float*)d_out;

    char* ws = (char*)d_ws;
    size_t off = 0;
    float* sume = (float*)(ws + off); off += (size_t)KCB * 4;
    float* sumx = (float*)(ws + off); off += (size_t)N_ROWS * 4;
    float* cd   = (float*)(ws + off); off += (size_t)N_ROWS * NSPLIT * 4;
    int*   ck   = (int*)  (ws + off); off += (size_t)N_ROWS * NSPLIT * 4;
    int*   inds = (int*)  (ws + off); off += (size_t)N_ROWS * 4;

    rownorm_kernel<<<KCB, 64, 0, stream>>>(emb, sume);
    rownorm_kernel<<<N_ROWS, 64, 0, stream>>>(lat, sumx);
    dim3 grid(N_ROWS / TM, NSPLIT);
    argmin_kernel<<<grid, 256, 0, stream>>>(lat, emb, sumx, sume, cd, ck);
    merge_kernel<<<N_ROWS / 256, 256, 0, stream>>>(cd, ck, inds);
    writeout_kernel<<<(N_ROWS * DIM / 4) / 256, 256, 0, stream>>>(lat, emb, inds, out);
}

// Round 3
// 3928.833 us; speedup vs baseline: 1.0195x; 1.0121x over previous
//
#include <hip/hip_runtime.h>
#include <float.h>

#define N_ROWS 32768
#define DIM    512
#define KCB    8192

#define TM 128      // rows per block
#define TK 256      // codes per k-tile
#define DC 32       // d-chunk staged in LDS
#define NSPLIT 4    // k-range splits across blockIdx.y
#define KT_PER_SPLIT ((KCB / NSPLIT) / TK)   // 8 k-tiles per block

// sum of squares of one 512-wide row per 64-thread block (fixed deterministic order)
__global__ __launch_bounds__(64) void rownorm_kernel(const float* __restrict__ src,
                                                     float* __restrict__ dst) {
    const int row  = blockIdx.x;
    const int lane = threadIdx.x;
    const float* p = src + (size_t)row * DIM;
    float s = 0.0f;
#pragma unroll
    for (int i = 0; i < DIM / 64; ++i) {
        float v = p[lane + i * 64];
        s = __builtin_fmaf(v, v, s);
    }
#pragma unroll
    for (int off = 32; off > 0; off >>= 1) s += __shfl_down(s, off, 64);
    if (lane == 0) dst[row] = s;
}

// distance-GEMM + running argmin over one k-split.
// amdgpu_waves_per_eu(2,2): pin the allocator to a 256-VGPR budget so the
// 8x16 accumulator microtile (128 regs) stays in registers. Round-2 evidence:
// __launch_bounds__(256,2) alone let LLVM target 4 waves/EU (128 VGPRs) and
// spill acc to scratch (WRITE_SIZE 163 MB).
__global__ __launch_bounds__(256)
__attribute__((amdgpu_waves_per_eu(2, 2)))
void argmin_kernel(const float* __restrict__ x,
                   const float* __restrict__ e,
                   const float* __restrict__ sumx,
                   const float* __restrict__ sume,
                   float* __restrict__ cand_d,
                   int* __restrict__ cand_k) {
    __shared__ float Xs[DC * TM];     // 16 KB
    __shared__ float Es[DC * TK];     // 32 KB
    __shared__ float rb[TM * 16];     // 8 KB
    __shared__ int   rk[TM * 16];     // 8 KB

    const int tid  = threadIdx.x;
    const int tx   = tid & 15;    // 16 k-groups of 16 codes
    const int ty   = tid >> 4;    // 16 row-groups of 8 rows
    const int row0 = blockIdx.x * TM;
    const int ks0  = blockIdx.y * (KCB / NSPLIT);

    // loop-invariant swizzled group bases (byte-XOR distributes over <<2)
    const int xg0 = (2 * ty) * 4;
    const int xg1 = (2 * ty + 1) * 4;
    int egb[4];
#pragma unroll
    for (int h = 0; h < 4; ++h) egb[h] = ((4 * tx + h) ^ (tx & 7)) * 4;

    float sxr[8];
    float best[8];
    int   bestk[8];
#pragma unroll
    for (int r = 0; r < 8; ++r) {
        sxr[r]   = sumx[row0 + ty * 8 + r];
        best[r]  = FLT_MAX;
        bestk[r] = 0;
    }

    for (int kt = 0; kt < KT_PER_SPLIT; ++kt) {
        const int k0 = ks0 + kt * TK;
        float acc[8][16];
#pragma unroll
        for (int r = 0; r < 8; ++r)
#pragma unroll
            for (int j = 0; j < 16; ++j) acc[r][j] = 0.0f;

        for (int ch = 0; ch < DIM / DC; ++ch) {
            const int d0 = ch * DC;
            __syncthreads();
            // ---- stage X: 128 rows x 32 d, 1024 float4, 8 lanes/row (128B segs)
#pragma unroll
            for (int i = 0; i < 4; ++i) {
                const int f   = i * 256 + tid;
                const int row = f >> 3;
                const int c4  = f & 7;
                const float4 v = *(const float4*)(x + (size_t)(row0 + row) * DIM + d0 + c4 * 4);
                const int swz = (((row >> 2) ^ c4) * 4) + (row & 3);
                Xs[(4 * c4 + 0) * TM + swz] = v.x;
                Xs[(4 * c4 + 1) * TM + swz] = v.y;
                Xs[(4 * c4 + 2) * TM + swz] = v.z;
                Xs[(4 * c4 + 3) * TM + swz] = v.w;
            }
            // ---- stage E: 256 k x 32 d, 2048 float4
#pragma unroll
            for (int i = 0; i < 8; ++i) {
                const int f  = i * 256 + tid;
                const int k  = f >> 3;
                const int c4 = f & 7;
                const float4 v = *(const float4*)(e + (size_t)(k0 + k) * DIM + d0 + c4 * 4);
                const int swz = ((((k >> 2) ^ ((k >> 4) & 7)) ^ c4) * 4) + (k & 3);
                Es[(4 * c4 + 0) * TK + swz] = v.x;
                Es[(4 * c4 + 1) * TK + swz] = v.y;
                Es[(4 * c4 + 2) * TK + swz] = v.z;
                Es[(4 * c4 + 3) * TK + swz] = v.w;
            }
            __syncthreads();
            // ---- compute: 32 d-steps, 8x16 FMA microtile per thread
            for (int c8 = 0; c8 < 8; ++c8) {
                const int kshift = c8 * 4;   // swizzle key for this dd quad
#pragma unroll
                for (int u = 0; u < 4; ++u) {
                    const int dd = c8 * 4 + u;
                    const float* xr = Xs + dd * TM;
                    const float* er = Es + dd * TK;
                    const float4 xa = *(const float4*)(xr + (xg0 ^ kshift));
                    const float4 xb = *(const float4*)(xr + (xg1 ^ kshift));
                    const float4 e0 = *(const float4*)(er + (egb[0] ^ kshift));
                    const float4 e1 = *(const float4*)(er + (egb[1] ^ kshift));
                    const float4 e2 = *(const float4*)(er + (egb[2] ^ kshift));
                    const float4 e3 = *(const float4*)(er + (egb[3] ^ kshift));
                    const float xv[8]  = {xa.x, xa.y, xa.z, xa.w, xb.x, xb.y, xb.z, xb.w};
                    const float ev[16] = {e0.x, e0.y, e0.z, e0.w, e1.x, e1.y, e1.z, e1.w,
                                          e2.x, e2.y, e2.z, e2.w, e3.x, e3.y, e3.z, e3.w};
#pragma unroll
                    for (int r = 0; r < 8; ++r)
#pragma unroll
                        for (int j = 0; j < 16; ++j)
                            acc[r][j] = __builtin_fmaf(xv[r], ev[j], acc[r][j]);
                }
            }
        }
        // ---- fold k-tile into running argmin (exact reference rounding sequence)
#pragma unroll
        for (int r = 0; r < 8; ++r) {
#pragma unroll
            for (int j = 0; j < 16; ++j) {
                const int k = k0 + 16 * tx + j;   // within-thread k ascending
                const float t1   = __fadd_rn(sxr[r], sume[k]);
                const float dist = __fsub_rn(t1, __fadd_rn(acc[r][j], acc[r][j]));
                if (dist < best[r]) { best[r] = dist; bestk[r] = k; }
            }
        }
    }

    __syncthreads();
#pragma unroll
    for (int r = 0; r < 8; ++r) {
        rb[(ty * 8 + r) * 16 + tx] = best[r];
        rk[(ty * 8 + r) * 16 + tx] = bestk[r];
    }
    __syncthreads();
    if (tid < TM) {
        float bd = rb[tid * 16 + 0];
        int   bk = rk[tid * 16 + 0];
#pragma unroll
        for (int t = 1; t < 16; ++t) {
            const float d = rb[tid * 16 + t];
            const int   k = rk[tid * 16 + t];
            if (d < bd || (d == bd && k < bk)) { bd = d; bk = k; }  // first occurrence
        }
        cand_d[(size_t)(row0 + tid) * NSPLIT + blockIdx.y] = bd;
        cand_k[(size_t)(row0 + tid) * NSPLIT + blockIdx.y] = bk;
    }
}

// merge per-split candidates -> final index (first-min semantics preserved:
// splits are ascending k-ranges, ties broken by lower k)
__global__ __launch_bounds__(256) void merge_kernel(const float* __restrict__ cand_d,
                                                    const int* __restrict__ cand_k,
                                                    int* __restrict__ inds) {
    const int row = blockIdx.x * 256 + threadIdx.x;
    float bd = cand_d[(size_t)row * NSPLIT];
    int   bk = cand_k[(size_t)row * NSPLIT];
#pragma unroll
    for (int s = 1; s < NSPLIT; ++s) {
        const float d = cand_d[(size_t)row * NSPLIT + s];
        const int   k = cand_k[(size_t)row * NSPLIT + s];
        if (d < bd || (d == bd && k < bk)) { bd = d; bk = k; }
    }
    inds[row] = bk;
}

// out = x + (e[ind] - x), exact elementwise fp32 replication of the STE
__global__ __launch_bounds__(256) void writeout_kernel(const float* __restrict__ x,
                                                       const float* __restrict__ e,
                                                       const int* __restrict__ inds,
                                                       float* __restrict__ out) {
    const int t  = blockIdx.x * blockDim.x + threadIdx.x;  // one float4 each
    const int n  = t >> 7;                                  // 128 float4 per row
    const int dq = (t & 127) * 4;
    const int ind = inds[n];
    const float4 xv = *(const float4*)(x + (size_t)n * DIM + dq);
    const float4 ev = *(const float4*)(e + (size_t)ind * DIM + dq);
    float4 o;
    o.x = __fadd_rn(xv.x, __fsub_rn(ev.x, xv.x));
    o.y = __fadd_rn(xv.y, __fsub_rn(ev.y, xv.y));
    o.z = __fadd_rn(xv.z, __fsub_rn(ev.z, xv.z));
    o.w = __fadd_rn(xv.w, __fsub_rn(ev.w, xv.w));
    *(float4*)(out + (size_t)n * DIM + dq) = o;
}

extern "C" void kernel_launch(void* const* d_in, const int* in_sizes, int n_in,
                              void* d_out, int out_size, void* d_ws, size_t ws_size,
                              hipStream_t stream) {
    const float* lat = (const float*)d_in[0];   // (16,2048,512) fp32
    const float* emb = (const float*)d_in[1];   // (8192,512) fp32
    float* out = (float*)d_out;

    char* ws = (char*)d_ws;
    size_t off = 0;
    float* sume = (float*)(ws + off); off += (size_t)KCB * 4;
    float* sumx = (float*)(ws + off); off += (size_t)N_ROWS * 4;
    float* cd   = (float*)(ws + off); off += (size_t)N_ROWS * NSPLIT * 4;
    int*   ck   = (int*)  (ws + off); off += (size_t)N_ROWS * NSPLIT * 4;
    int*   inds = (int*)  (ws + off); off += (size_t)N_ROWS * 4;

    rownorm_kernel<<<KCB, 64, 0, stream>>>(emb, sume);
    rownorm_kernel<<<N_ROWS, 64, 0, stream>>>(lat, sumx);
    dim3 grid(N_ROWS / TM, NSPLIT);
    argmin_kernel<<<grid, 256, 0, stream>>>(lat, emb, sumx, sume, cd, ck);
    merge_kernel<<<N_ROWS / 256, 256, 0, stream>>>(cd, ck, inds);
    writeout_kernel<<<(N_ROWS * DIM / 4) / 256, 256, 0, stream>>>(lat, emb, inds, out);
}

// Round 4
// 1337.130 us; speedup vs baseline: 2.9955x; 2.9383x over previous
//
#include <hip/hip_runtime.h>
#include <hip/hip_bf16.h>
#include <float.h>

#define NR    32768
#define DDIM  512
#define KC    8192
#define NTILE 64      // KC / 128 code-tiles

typedef __attribute__((ext_vector_type(8))) short short8;   // 8 bf16 = 4 VGPR
typedef __attribute__((ext_vector_type(4))) float f32x4;

// pack two fp32 -> two bf16 (RNE) in one u32 (low word = first element)
__device__ inline unsigned cvt2(float a, float b) {
    __hip_bfloat162 h = __float22bfloat162_rn(float2{a, b});
    union { __hip_bfloat162 h; unsigned u; } v; v.h = h;
    return v.u;
}

// sum of squares, one row per 64-thread block. MUST stay bitwise-identical to
// rounds 1-3 (its rounding is baked into the verified-passing dist values).
__global__ __launch_bounds__(64) void rownorm_kernel(const float* __restrict__ src,
                                                     float* __restrict__ dst) {
    const int row  = blockIdx.x;
    const int lane = threadIdx.x;
    const float* p = src + (size_t)row * DDIM;
    float s = 0.0f;
#pragma unroll
    for (int i = 0; i < DDIM / 64; ++i) {
        float v = p[lane + i * 64];
        s = __builtin_fmaf(v, v, s);
    }
#pragma unroll
    for (int off = 32; off > 0; off >>= 1) s += __shfl_down(s, off, 64);
    if (lane == 0) dst[row] = s;
}

__global__ __launch_bounds__(256) void semax_kernel(const float* __restrict__ sume,
                                                    float* __restrict__ semax) {
    __shared__ float red[256];
    float m = 0.f;
    for (int i = threadIdx.x; i < KC; i += 256) m = fmaxf(m, sume[i]);
    red[threadIdx.x] = m;
    __syncthreads();
    for (int s = 128; s > 0; s >>= 1) {
        if (threadIdx.x < s) red[threadIdx.x] = fmaxf(red[threadIdx.x], red[threadIdx.x + s]);
        __syncthreads();
    }
    if (threadIdx.x == 0) semax[0] = sqrtf(red[0]);
}

// bf16 MFMA approx-score GEMM + per-(row, code-tile) (min, argmin, 2ndmin).
// Tile 128x128, BK=32. LDS granule-swizzled: granule' = g ^ ((row>>1)&3)
// -> frag ds_read_b128 and staging stores are <=2-way (free).
__global__ __launch_bounds__(256) void gemm_filter_kernel(
        const float* __restrict__ x, const float* __restrict__ e,
        const float* __restrict__ sume,
        float* __restrict__ lmin, float* __restrict__ l2nd, int* __restrict__ lidx) {
    __shared__ unsigned Xs[128 * 16];   // 128 rows x 32 bf16 (16 u32), 8 KB
    __shared__ unsigned Es[128 * 16];   // 8 KB
    __shared__ float ev1[2][128];
    __shared__ float ev2[2][128];
    __shared__ int   ek1[2][128];

    const int tid  = threadIdx.x;
    const int nb   = blockIdx.x & (NTILE - 1);
    const int mb   = blockIdx.x >> 6;
    const int row0 = mb * 128, col0 = nb * 128;
    const int lane = tid & 63, w = tid >> 6;
    const int wy = w >> 1, wx = w & 1;
    const int l15 = lane & 15, q = lane >> 4;

    f32x4 acc[4][4];
#pragma unroll
    for (int i = 0; i < 4; ++i)
#pragma unroll
        for (int j = 0; j < 4; ++j) acc[i][j] = f32x4{0.f, 0.f, 0.f, 0.f};

    for (int it = 0; it < 16; ++it) {
        const int d0 = it * 32;
        __syncthreads();
        // stage X and E: 512 granules (8 floats -> 8 bf16) each, 2 per thread per tile
#pragma unroll
        for (int i = 0; i < 2; ++i) {
            const int gid = i * 256 + tid;
            const int r = gid >> 2, g = gid & 3;
            const int gsw = g ^ ((r >> 1) & 3);
            {
                const float* src = x + (size_t)(row0 + r) * DDIM + d0 + 8 * g;
                const float4 a = *(const float4*)src;
                const float4 b = *(const float4*)(src + 4);
                unsigned* dst = &Xs[r * 16 + gsw * 4];
                dst[0] = cvt2(a.x, a.y); dst[1] = cvt2(a.z, a.w);
                dst[2] = cvt2(b.x, b.y); dst[3] = cvt2(b.z, b.w);
            }
            {
                const float* src = e + (size_t)(col0 + r) * DDIM + d0 + 8 * g;
                const float4 a = *(const float4*)src;
                const float4 b = *(const float4*)(src + 4);
                unsigned* dst = &Es[r * 16 + gsw * 4];
                dst[0] = cvt2(a.x, a.y); dst[1] = cvt2(a.z, a.w);
                dst[2] = cvt2(b.x, b.y); dst[3] = cvt2(b.z, b.w);
            }
        }
        __syncthreads();
        short8 A[4], B[4];
#pragma unroll
        for (int i = 0; i < 4; ++i) {
            const int ra = 64 * wy + 16 * i + l15;
            A[i] = *(const short8*)(&Xs[ra * 16 + (q ^ ((ra >> 1) & 3)) * 4]);
            const int rb = 64 * wx + 16 * i + l15;
            B[i] = *(const short8*)(&Es[rb * 16 + (q ^ ((rb >> 1) & 3)) * 4]);
        }
#pragma unroll
        for (int i = 0; i < 4; ++i)
#pragma unroll
            for (int j = 0; j < 4; ++j)
                acc[i][j] = __builtin_amdgcn_mfma_f32_16x16x32_bf16(A[i], B[j], acc[i][j], 0, 0, 0);
    }

    // ---- epilogue: per-row (min, argmin, 2ndmin) over this 128-code tile
    float se[4];
#pragma unroll
    for (int j = 0; j < 4; ++j) se[j] = sume[col0 + 64 * wx + 16 * j + l15];

    __syncthreads();
#pragma unroll
    for (int i = 0; i < 4; ++i) {
#pragma unroll
        for (int reg = 0; reg < 4; ++reg) {
            float v1 = FLT_MAX, v2 = FLT_MAX; int k1 = 0;
#pragma unroll
            for (int j = 0; j < 4; ++j) {
                const float s = __builtin_fmaf(-2.f, acc[i][j][reg], se[j]);
                const int c = col0 + 64 * wx + 16 * j + l15;
                if (s < v1) { v2 = v1; v1 = s; k1 = c; }
                else        { v2 = fminf(v2, s); }
            }
#pragma unroll
            for (int m = 1; m <= 8; m <<= 1) {
                const float ov1 = __shfl_xor(v1, m, 64);
                const int   ok1 = __shfl_xor(k1, m, 64);
                const float ov2 = __shfl_xor(v2, m, 64);
                const float nv2 = fminf(fmaxf(v1, ov1), fminf(v2, ov2));
                if (ov1 < v1) { v1 = ov1; k1 = ok1; }
                v2 = nv2;
            }
            const int rl = 64 * wy + 16 * i + 4 * q + reg;
            if (l15 == 0) { ev1[wx][rl] = v1; ek1[wx][rl] = k1; ev2[wx][rl] = v2; }
        }
    }
    __syncthreads();
    if (tid < 128) {
        const float a1 = ev1[0][tid], b1 = ev1[1][tid];
        const float a2 = ev2[0][tid], b2 = ev2[1][tid];
        const int   ak = ek1[0][tid], bk = ek1[1][tid];
        float gv1, gv2; int gk1;
        if (b1 < a1) { gv1 = b1; gk1 = bk; gv2 = fminf(fminf(a1, a2), b2); }
        else         { gv1 = a1; gk1 = ak; gv2 = fminf(fminf(b1, a2), b2); }
        const size_t o = (size_t)(row0 + tid) * NTILE + nb;
        lmin[o] = gv1; l2nd[o] = gv2; lidx[o] = gk1;
    }
}

// exact rescore of provably-covering candidate set; one wave per row.
__global__ __launch_bounds__(256) void rescore_kernel(
        const float* __restrict__ x, const float* __restrict__ e,
        const float* __restrict__ sumx, const float* __restrict__ sume,
        const float* __restrict__ semax,
        const float* __restrict__ lmin, const float* __restrict__ l2nd,
        const int* __restrict__ lidx, int* __restrict__ inds) {
    __shared__ float xr[4][DDIM];
    __shared__ int list[4][64];

    const int w = threadIdx.x >> 6, lane = threadIdx.x & 63;
    const int row = blockIdx.x * 4 + w;

    const float lm = lmin[(size_t)row * NTILE + lane];
    const float l2 = l2nd[(size_t)row * NTILE + lane];
    const int   li = lidx[(size_t)row * NTILE + lane];

    float mr = lm;
#pragma unroll
    for (int m = 1; m < 64; m <<= 1) mr = fminf(mr, __shfl_xor(mr, m, 64));

    const float sx  = sumx[row];
    const float thr = mr + (0.03125f * sqrtf(sx) * semax[0] + 2.5e-4f);

    const bool single = (lm <= thr) && (l2 > thr);
    const unsigned long long bs = __ballot(single);
    const int pos = __popcll(bs & ((1ull << lane) - 1ull));
    if (single) list[w][pos] = li;
    const int nS = __popcll(bs);
    unsigned long long bf = __ballot(l2 <= thr);

    // stage x row (read later broadcast-style; wave-synchronous, barrier for rigor)
    {
        const float* px = x + (size_t)row * DDIM + lane * 8;
        *(float4*)(&xr[w][lane * 8])     = *(const float4*)(px);
        *(float4*)(&xr[w][lane * 8 + 4]) = *(const float4*)(px + 4);
    }
    __syncthreads();

    float bd = FLT_MAX; int bk = 0x7fffffff;
    // exact dist: identical op sequence to rounds 1-3 (sequential fp32 FMA over d)
#define EVAL(KK)                                                            \
    {                                                                       \
        const int k_ = (KK);                                                \
        const float* ep = e + (size_t)k_ * DDIM;                            \
        float dot = 0.f;                                                    \
        _Pragma("unroll 8")                                                 \
        for (int d = 0; d < DDIM; ++d) dot = __builtin_fmaf(xr[w][d], ep[d], dot); \
        const float t1   = __fadd_rn(sx, sume[k_]);                         \
        const float dist = __fsub_rn(t1, __fadd_rn(dot, dot));              \
        if (dist < bd || (dist == bd && k_ < bk)) { bd = dist; bk = k_; }   \
    }

    if (lane < nS) EVAL(list[w][lane]);
    while (bf) {
        const int t = __ffsll((long long)bf) - 1;
        bf &= bf - 1;
        EVAL(128 * t + lane);
        EVAL(128 * t + 64 + lane);
    }
#undef EVAL

#pragma unroll
    for (int m = 1; m < 64; m <<= 1) {
        const float od = __shfl_xor(bd, m, 64);
        const int   ok = __shfl_xor(bk, m, 64);
        if (od < bd || (od == bd && ok < bk)) { bd = od; bk = ok; }
    }
    if (lane == 0) inds[row] = bk;
}

// out = x + (e[ind] - x), exact elementwise fp32 STE
__global__ __launch_bounds__(256) void writeout_kernel(const float* __restrict__ x,
                                                       const float* __restrict__ e,
                                                       const int* __restrict__ inds,
                                                       float* __restrict__ out) {
    const int t  = blockIdx.x * blockDim.x + threadIdx.x;
    const int n  = t >> 7;
    const int dq = (t & 127) * 4;
    const int ind = inds[n];
    const float4 xv = *(const float4*)(x + (size_t)n * DDIM + dq);
    const float4 ev = *(const float4*)(e + (size_t)ind * DDIM + dq);
    float4 o;
    o.x = __fadd_rn(xv.x, __fsub_rn(ev.x, xv.x));
    o.y = __fadd_rn(xv.y, __fsub_rn(ev.y, xv.y));
    o.z = __fadd_rn(xv.z, __fsub_rn(ev.z, xv.z));
    o.w = __fadd_rn(xv.w, __fsub_rn(ev.w, xv.w));
    *(float4*)(out + (size_t)n * DDIM + dq) = o;
}

extern "C" void kernel_launch(void* const* d_in, const int* in_sizes, int n_in,
                              void* d_out, int out_size, void* d_ws, size_t ws_size,
                              hipStream_t stream) {
    const float* lat = (const float*)d_in[0];   // (16,2048,512) fp32
    const float* emb = (const float*)d_in[1];   // (8192,512) fp32
    float* out = (float*)d_out;

    char* ws = (char*)d_ws;
    size_t off = 0;
    float* sume  = (float*)(ws + off); off += (size_t)KC * 4;
    float* sumx  = (float*)(ws + off); off += (size_t)NR * 4;
    float* semax = (float*)(ws + off); off += 256;
    float* lmin  = (float*)(ws + off); off += (size_t)NR * NTILE * 4;
    float* l2nd  = (float*)(ws + off); off += (size_t)NR * NTILE * 4;
    int*   lidx  = (int*)  (ws + off); off += (size_t)NR * NTILE * 4;
    int*   inds  = (int*)  (ws + off); off += (size_t)NR * 4;

    rownorm_kernel<<<KC, 64, 0, stream>>>(emb, sume);
    rownorm_kernel<<<NR, 64, 0, stream>>>(lat, sumx);
    semax_kernel<<<1, 256, 0, stream>>>(sume, semax);
    gemm_filter_kernel<<<(NR / 128) * NTILE, 256, 0, stream>>>(lat, emb, sume, lmin, l2nd, lidx);
    rescore_kernel<<<NR / 4, 256, 0, stream>>>(lat, emb, sumx, sume, semax, lmin, l2nd, lidx, inds);
    writeout_kernel<<<(NR * DDIM / 4) / 256, 256, 0, stream>>>(lat, emb, inds, out);
}

// Round 5
// 1072.783 us; speedup vs baseline: 3.7336x; 1.2464x over previous
//
#include <hip/hip_runtime.h>
#include <hip/hip_bf16.h>
#include <float.h>

#define NR    32768
#define DDIM  512
#define KC    8192
#define NTILE 64      // KC / 128 code-tiles

typedef __attribute__((ext_vector_type(8))) short short8;   // 8 bf16 = 4 VGPR
typedef __attribute__((ext_vector_type(4))) float f32x4;
typedef const __attribute__((address_space(1))) char gchar_t;
typedef __attribute__((address_space(3))) char lchar_t;

// pack two fp32 -> two bf16 (RNE) in one u32 (low word = first element)
__device__ inline unsigned cvt2(float a, float b) {
    __hip_bfloat162 h = __float22bfloat162_rn(float2{a, b});
    union { __hip_bfloat162 h; unsigned u; } v; v.h = h;
    return v.u;
}

// fp32 -> bf16 (RNE) pre-conversion, one 16B output granule per thread
__global__ __launch_bounds__(256) void cvt_bf16_kernel(const float* __restrict__ src,
                                                       unsigned* __restrict__ dst) {
    const int t = blockIdx.x * 256 + threadIdx.x;
    const float4 a = *(const float4*)(src + (size_t)t * 8);
    const float4 b = *(const float4*)(src + (size_t)t * 8 + 4);
    uint4 o;
    o.x = cvt2(a.x, a.y); o.y = cvt2(a.z, a.w);
    o.z = cvt2(b.x, b.y); o.w = cvt2(b.z, b.w);
    *(uint4*)(dst + (size_t)t * 4) = o;
}

// sum of squares, one row per 64-thread block. Bitwise-identical to rounds 1-4.
__global__ __launch_bounds__(64) void rownorm_kernel(const float* __restrict__ src,
                                                     float* __restrict__ dst) {
    const int row  = blockIdx.x;
    const int lane = threadIdx.x;
    const float* p = src + (size_t)row * DDIM;
    float s = 0.0f;
#pragma unroll
    for (int i = 0; i < DDIM / 64; ++i) {
        float v = p[lane + i * 64];
        s = __builtin_fmaf(v, v, s);
    }
#pragma unroll
    for (int off = 32; off > 0; off >>= 1) s += __shfl_down(s, off, 64);
    if (lane == 0) dst[row] = s;
}

__global__ __launch_bounds__(256) void semax_kernel(const float* __restrict__ sume,
                                                    float* __restrict__ semax) {
    __shared__ float red[256];
    float m = 0.f;
    for (int i = threadIdx.x; i < KC; i += 256) m = fmaxf(m, sume[i]);
    red[threadIdx.x] = m;
    __syncthreads();
    for (int s = 128; s > 0; s >>= 1) {
        if (threadIdx.x < s) red[threadIdx.x] = fmaxf(red[threadIdx.x], red[threadIdx.x + s]);
        __syncthreads();
    }
    if (threadIdx.x == 0) semax[0] = sqrtf(red[0]);
}

// bf16 MFMA approx-score GEMM (pre-converted bf16 inputs, global_load_lds
// width-16 staging, BK=64) + per-(row, code-tile) (min, argmin, 2ndmin).
// LDS granule layout: granule(q,row) at offset (q*128+row)*16 bytes, q = k-octet.
//  - DMA: inst (w,t) stages granules [(w*4+t)*64, +64) -> uniform q, rows=lane.
//  - frag ds_read_b128: bank = (row*4)%32 -> uniformly dense, conflict-free.
__global__ __launch_bounds__(256) void gemm_filter_kernel(
        const unsigned* __restrict__ xb, const unsigned* __restrict__ eb,
        const float* __restrict__ sume,
        float* __restrict__ lmin, float* __restrict__ l2nd, int* __restrict__ lidx) {
    __shared__ alignas(16) char Xs[16384];   // 128 rows x 64 bf16
    __shared__ alignas(16) char Es[16384];   // 128 cols x 64 bf16
    __shared__ float ev1[2][128];
    __shared__ float ev2[2][128];
    __shared__ int   ek1[2][128];

    const int tid  = threadIdx.x;
    const int nb   = blockIdx.x & (NTILE - 1);
    const int mb   = blockIdx.x >> 6;
    const int row0 = mb * 128, col0 = nb * 128;
    const int lane = tid & 63, w = tid >> 6;
    const int wy = w >> 1, wx = w & 1;
    const int l15 = lane & 15, q4 = lane >> 4;   // q4 in [0,4)

    f32x4 acc[4][4];
#pragma unroll
    for (int i = 0; i < 4; ++i)
#pragma unroll
        for (int j = 0; j < 4; ++j) acc[i][j] = f32x4{0.f, 0.f, 0.f, 0.f};

    for (int it = 0; it < 8; ++it) {
        const int dbyte = it * 128;          // 64 bf16 per K-iter
        __syncthreads();                      // prev compute done before overwrite
#pragma unroll
        for (int t = 0; t < 4; ++t) {
            const int gi  = (w * 4 + t) * 64 + lane;   // granule index
            const int q   = gi >> 7;                    // uniform within wave-inst
            const int row = gi & 127;
            const char* gx = (const char*)xb + (((size_t)(row0 + row)) << 10) + dbyte + (q << 4);
            __builtin_amdgcn_global_load_lds((gchar_t*)gx,
                (lchar_t*)(Xs + (w * 4 + t) * 1024), 16, 0, 0);
            const char* ge = (const char*)eb + (((size_t)(col0 + row)) << 10) + dbyte + (q << 4);
            __builtin_amdgcn_global_load_lds((gchar_t*)ge,
                (lchar_t*)(Es + (w * 4 + t) * 1024), 16, 0, 0);
        }
        __syncthreads();                      // drains vmcnt -> LDS visible
#pragma unroll
        for (int ks = 0; ks < 2; ++ks) {
            short8 A[4], B[4];
            const int qg = ks * 4 + q4;
#pragma unroll
            for (int i = 0; i < 4; ++i) {
                const int ra = 64 * wy + 16 * i + l15;
                A[i] = *(const short8*)(Xs + (qg * 128 + ra) * 16);
                const int rb = 64 * wx + 16 * i + l15;
                B[i] = *(const short8*)(Es + (qg * 128 + rb) * 16);
            }
#pragma unroll
            for (int i = 0; i < 4; ++i)
#pragma unroll
                for (int j = 0; j < 4; ++j)
                    acc[i][j] = __builtin_amdgcn_mfma_f32_16x16x32_bf16(A[i], B[j], acc[i][j], 0, 0, 0);
        }
    }

    // ---- epilogue: per-row (min, argmin, 2ndmin) over this 128-code tile
    float se[4];
#pragma unroll
    for (int j = 0; j < 4; ++j) se[j] = sume[col0 + 64 * wx + 16 * j + l15];

    __syncthreads();
#pragma unroll
    for (int i = 0; i < 4; ++i) {
#pragma unroll
        for (int reg = 0; reg < 4; ++reg) {
            float v1 = FLT_MAX, v2 = FLT_MAX; int k1 = 0;
#pragma unroll
            for (int j = 0; j < 4; ++j) {
                const float s = __builtin_fmaf(-2.f, acc[i][j][reg], se[j]);
                const int c = col0 + 64 * wx + 16 * j + l15;
                if (s < v1) { v2 = v1; v1 = s; k1 = c; }
                else        { v2 = fminf(v2, s); }
            }
#pragma unroll
            for (int m = 1; m <= 8; m <<= 1) {
                const float ov1 = __shfl_xor(v1, m, 64);
                const int   ok1 = __shfl_xor(k1, m, 64);
                const float ov2 = __shfl_xor(v2, m, 64);
                const float nv2 = fminf(fmaxf(v1, ov1), fminf(v2, ov2));
                if (ov1 < v1) { v1 = ov1; k1 = ok1; }
                v2 = nv2;
            }
            const int rl = 64 * wy + 16 * i + 4 * q4 + reg;
            if (l15 == 0) { ev1[wx][rl] = v1; ek1[wx][rl] = k1; ev2[wx][rl] = v2; }
        }
    }
    __syncthreads();
    if (tid < 128) {
        const float a1 = ev1[0][tid], b1 = ev1[1][tid];
        const float a2 = ev2[0][tid], b2 = ev2[1][tid];
        const int   ak = ek1[0][tid], bk = ek1[1][tid];
        float gv1, gv2; int gk1;
        if (b1 < a1) { gv1 = b1; gk1 = bk; gv2 = fminf(fminf(a1, a2), b2); }
        else         { gv1 = a1; gk1 = ak; gv2 = fminf(fminf(b1, a2), b2); }
        const size_t o = (size_t)(row0 + tid) * NTILE + nb;
        lmin[o] = gv1; l2nd[o] = gv2; lidx[o] = gk1;
    }
}

// exact rescore of provably-covering candidate set; one wave per row.
// margin = 2*(2^-7*||x||*||e||max + 6.5e-5): bf16-RNE dot error bound (2^-8
// rel per operand pair, doubled for the -2 factor) + two half-ulp(512)
// roundings in the exact-dist formula; doubled for the two-sided argument.
__global__ __launch_bounds__(256) void rescore_kernel(
        const float* __restrict__ x, const float* __restrict__ e,
        const float* __restrict__ sumx, const float* __restrict__ sume,
        const float* __restrict__ semax,
        const float* __restrict__ lmin, const float* __restrict__ l2nd,
        const int* __restrict__ lidx, int* __restrict__ inds) {
    __shared__ float xr[4][DDIM];
    __shared__ int list[4][64];

    const int w = threadIdx.x >> 6, lane = threadIdx.x & 63;
    const int row = blockIdx.x * 4 + w;

    const float lm = lmin[(size_t)row * NTILE + lane];
    const float l2 = l2nd[(size_t)row * NTILE + lane];
    const int   li = lidx[(size_t)row * NTILE + lane];

    float mr = lm;
#pragma unroll
    for (int m = 1; m < 64; m <<= 1) mr = fminf(mr, __shfl_xor(mr, m, 64));

    const float sx  = sumx[row];
    const float thr = mr + (0.0157f * sqrtf(sx) * semax[0] + 1.4e-4f);

    const bool single = (lm <= thr) && (l2 > thr);
    const unsigned long long bs = __ballot(single);
    const int pos = __popcll(bs & ((1ull << lane) - 1ull));
    if (single) list[w][pos] = li;
    const int nS = __popcll(bs);
    unsigned long long bf = __ballot(l2 <= thr);

    {
        const float* px = x + (size_t)row * DDIM + lane * 8;
        *(float4*)(&xr[w][lane * 8])     = *(const float4*)(px);
        *(float4*)(&xr[w][lane * 8 + 4]) = *(const float4*)(px + 4);
    }
    __syncthreads();

    float bd = FLT_MAX; int bk = 0x7fffffff;
    // exact dist: float4 loads, but FMA order identical to rounds 1-4
#define EVAL(KK)                                                             \
    {                                                                        \
        const int k_ = (KK);                                                 \
        const float4* ep4 = (const float4*)(e + ((size_t)k_ << 9));          \
        float dot = 0.f;                                                     \
        _Pragma("unroll 4")                                                  \
        for (int d4 = 0; d4 < 128; ++d4) {                                   \
            const float4 ev = ep4[d4];                                       \
            const float4 xv = *(const float4*)(&xr[w][d4 * 4]);              \
            dot = __builtin_fmaf(xv.x, ev.x, dot);                           \
            dot = __builtin_fmaf(xv.y, ev.y, dot);                           \
            dot = __builtin_fmaf(xv.z, ev.z, dot);                           \
            dot = __builtin_fmaf(xv.w, ev.w, dot);                           \
        }                                                                    \
        const float t1   = __fadd_rn(sx, sume[k_]);                          \
        const float dist = __fsub_rn(t1, __fadd_rn(dot, dot));               \
        if (dist < bd || (dist == bd && k_ < bk)) { bd = dist; bk = k_; }    \
    }

    if (lane < nS) EVAL(list[w][lane]);
    while (bf) {
        const int t = __ffsll((long long)bf) - 1;
        bf &= bf - 1;
        EVAL(128 * t + lane);
        EVAL(128 * t + 64 + lane);
    }
#undef EVAL

#pragma unroll
    for (int m = 1; m < 64; m <<= 1) {
        const float od = __shfl_xor(bd, m, 64);
        const int   ok = __shfl_xor(bk, m, 64);
        if (od < bd || (od == bd && ok < bk)) { bd = od; bk = ok; }
    }
    if (lane == 0) inds[row] = bk;
}

// out = x + (e[ind] - x), exact elementwise fp32 STE
__global__ __launch_bounds__(256) void writeout_kernel(const float* __restrict__ x,
                                                       const float* __restrict__ e,
                                                       const int* __restrict__ inds,
                                                       float* __restrict__ out) {
    const int t  = blockIdx.x * blockDim.x + threadIdx.x;
    const int n  = t >> 7;
    const int dq = (t & 127) * 4;
    const int ind = inds[n];
    const float4 xv = *(const float4*)(x + (size_t)n * DDIM + dq);
    const float4 ev = *(const float4*)(e + (size_t)ind * DDIM + dq);
    float4 o;
    o.x = __fadd_rn(xv.x, __fsub_rn(ev.x, xv.x));
    o.y = __fadd_rn(xv.y, __fsub_rn(ev.y, xv.y));
    o.z = __fadd_rn(xv.z, __fsub_rn(ev.z, xv.z));
    o.w = __fadd_rn(xv.w, __fsub_rn(ev.w, xv.w));
    *(float4*)(out + (size_t)n * DDIM + dq) = o;
}

extern "C" void kernel_launch(void* const* d_in, const int* in_sizes, int n_in,
                              void* d_out, int out_size, void* d_ws, size_t ws_size,
                              hipStream_t stream) {
    const float* lat = (const float*)d_in[0];   // (16,2048,512) fp32
    const float* emb = (const float*)d_in[1];   // (8192,512) fp32
    float* out = (float*)d_out;

    char* ws = (char*)d_ws;
    size_t off = 0;
    float*    sume  = (float*)(ws + off);    off += (size_t)KC * 4;
    float*    sumx  = (float*)(ws + off);    off += (size_t)NR * 4;
    float*    semax = (float*)(ws + off);    off += 256;
    float*    lmin  = (float*)(ws + off);    off += (size_t)NR * NTILE * 4;
    float*    l2nd  = (float*)(ws + off);    off += (size_t)NR * NTILE * 4;
    int*      lidx  = (int*)  (ws + off);    off += (size_t)NR * NTILE * 4;
    int*      inds  = (int*)  (ws + off);    off += (size_t)NR * 4;
    unsigned* xb    = (unsigned*)(ws + off); off += (size_t)NR * DDIM * 2;
    unsigned* eb    = (unsigned*)(ws + off); off += (size_t)KC * DDIM * 2;

    cvt_bf16_kernel<<<(NR * DDIM / 8) / 256, 256, 0, stream>>>(lat, xb);
    cvt_bf16_kernel<<<(KC * DDIM / 8) / 256, 256, 0, stream>>>(emb, eb);
    rownorm_kernel<<<KC, 64, 0, stream>>>(emb, sume);
    rownorm_kernel<<<NR, 64, 0, stream>>>(lat, sumx);
    semax_kernel<<<1, 256, 0, stream>>>(sume, semax);
    gemm_filter_kernel<<<(NR / 128) * NTILE, 256, 0, stream>>>(xb, eb, sume, lmin, l2nd, lidx);
    rescore_kernel<<<NR / 4, 256, 0, stream>>>(lat, emb, sumx, sume, semax, lmin, l2nd, lidx, inds);
    writeout_kernel<<<(NR * DDIM / 4) / 256, 256, 0, stream>>>(lat, emb, inds, out);
}

// Round 6
// 894.596 us; speedup vs baseline: 4.4773x; 1.1992x over previous
//
#include <hip/hip_runtime.h>
#include <hip/hip_bf16.h>
#include <float.h>

#define NR    32768
#define DDIM  512
#define KC    8192
#define NTILE 64      // KC / 128 code-tiles

typedef __attribute__((ext_vector_type(8))) short short8;   // 8 bf16 = 4 VGPR
typedef __attribute__((ext_vector_type(4))) float f32x4;
typedef const __attribute__((address_space(1))) char gchar_t;
typedef __attribute__((address_space(3))) char lchar_t;

// pack two fp32 -> two bf16 (RNE) in one u32 (low word = first element)
__device__ inline unsigned cvt2(float a, float b) {
    __hip_bfloat162 h = __float22bfloat162_rn(float2{a, b});
    union { __hip_bfloat162 h; unsigned u; } v; v.h = h;
    return v.u;
}

// fp32 -> bf16 (RNE) pre-conversion, one 16B output granule per thread
__global__ __launch_bounds__(256) void cvt_bf16_kernel(const float* __restrict__ src,
                                                       unsigned* __restrict__ dst) {
    const int t = blockIdx.x * 256 + threadIdx.x;
    const float4 a = *(const float4*)(src + (size_t)t * 8);
    const float4 b = *(const float4*)(src + (size_t)t * 8 + 4);
    uint4 o;
    o.x = cvt2(a.x, a.y); o.y = cvt2(a.z, a.w);
    o.z = cvt2(b.x, b.y); o.w = cvt2(b.z, b.w);
    *(uint4*)(dst + (size_t)t * 4) = o;
}

// sum of squares, one row per 64-thread block. Bitwise-identical to rounds 1-5.
__global__ __launch_bounds__(64) void rownorm_kernel(const float* __restrict__ src,
                                                     float* __restrict__ dst) {
    const int row  = blockIdx.x;
    const int lane = threadIdx.x;
    const float* p = src + (size_t)row * DDIM;
    float s = 0.0f;
#pragma unroll
    for (int i = 0; i < DDIM / 64; ++i) {
        float v = p[lane + i * 64];
        s = __builtin_fmaf(v, v, s);
    }
#pragma unroll
    for (int off = 32; off > 0; off >>= 1) s += __shfl_down(s, off, 64);
    if (lane == 0) dst[row] = s;
}

__global__ __launch_bounds__(256) void semax_kernel(const float* __restrict__ sume,
                                                    float* __restrict__ semax) {
    __shared__ float red[256];
    float m = 0.f;
    for (int i = threadIdx.x; i < KC; i += 256) m = fmaxf(m, sume[i]);
    red[threadIdx.x] = m;
    __syncthreads();
    for (int s = 128; s > 0; s >>= 1) {
        if (threadIdx.x < s) red[threadIdx.x] = fmaxf(red[threadIdx.x], red[threadIdx.x + s]);
        __syncthreads();
    }
    if (threadIdx.x == 0) semax[0] = sqrtf(red[0]);
}

// bf16 MFMA approx-score GEMM + per-(row, code-tile) (min, argmin, 2ndmin).
// Staging (fixed from round 5's scattered DMA): one global_load_lds covers
// 8 rows x 128 contiguous bytes (8 lanes/row, source octet (L&7)^(L>>3)) ->
// 16 fully-used 64B lines per instruction, zero over-fetch. Implied LDS
// layout: octet (ra, q) lives at 16B-slot ra*8 + (q ^ (ra&7)) -> frag
// ds_read_b128 hits all 32 banks uniformly (conflict-free throughput regime).
__global__ __launch_bounds__(256) void gemm_filter_kernel(
        const unsigned* __restrict__ xb, const unsigned* __restrict__ eb,
        const float* __restrict__ sume,
        float* __restrict__ lmin, float* __restrict__ l2nd, int* __restrict__ lidx) {
    __shared__ alignas(16) char Xs[16384];   // 128 rows x 64 bf16
    __shared__ alignas(16) char Es[16384];   // 128 cols x 64 bf16
    __shared__ float ev1[2][128];
    __shared__ float ev2[2][128];
    __shared__ int   ek1[2][128];

    const int tid  = threadIdx.x;
    const int nb   = blockIdx.x & (NTILE - 1);
    const int mb   = blockIdx.x >> 6;
    const int row0 = mb * 128, col0 = nb * 128;
    const int lane = tid & 63, w = tid >> 6;
    const int wy = w >> 1, wx = w & 1;
    const int l15 = lane & 15, q4 = lane >> 4;   // q4 in [0,4)
    const int rl  = lane >> 3;                   // DMA: row within 8-row group
    const int qs  = (lane & 7) ^ rl;             // DMA: permuted source octet

    f32x4 acc[4][4];
#pragma unroll
    for (int i = 0; i < 4; ++i)
#pragma unroll
        for (int j = 0; j < 4; ++j) acc[i][j] = f32x4{0.f, 0.f, 0.f, 0.f};

    for (int it = 0; it < 8; ++it) {
        const int dbyte = it * 128;          // 64 bf16 per K-iter
        __syncthreads();                      // prev compute done before overwrite
#pragma unroll
        for (int t = 0; t < 4; ++t) {
            const int rbase = (w * 4 + t) * 8;     // 8 rows per instruction
            const char* gx = (const char*)xb
                + (((size_t)(row0 + rbase + rl)) << 10) + dbyte + (qs << 4);
            __builtin_amdgcn_global_load_lds((gchar_t*)gx,
                (lchar_t*)(Xs + (w * 4 + t) * 1024), 16, 0, 0);
            const char* ge = (const char*)eb
                + (((size_t)(col0 + rbase + rl)) << 10) + dbyte + (qs << 4);
            __builtin_amdgcn_global_load_lds((gchar_t*)ge,
                (lchar_t*)(Es + (w * 4 + t) * 1024), 16, 0, 0);
        }
        __syncthreads();                      // drains vmcnt -> LDS visible
#pragma unroll
        for (int ks = 0; ks < 2; ++ks) {
            short8 A[4], B[4];
            const int qg = ks * 4 + q4;
#pragma unroll
            for (int i = 0; i < 4; ++i) {
                const int ra = 64 * wy + 16 * i + l15;
                A[i] = *(const short8*)(Xs + (ra * 8 + (qg ^ (ra & 7))) * 16);
                const int rb = 64 * wx + 16 * i + l15;
                B[i] = *(const short8*)(Es + (rb * 8 + (qg ^ (rb & 7))) * 16);
            }
#pragma unroll
            for (int i = 0; i < 4; ++i)
#pragma unroll
                for (int j = 0; j < 4; ++j)
                    acc[i][j] = __builtin_amdgcn_mfma_f32_16x16x32_bf16(A[i], B[j], acc[i][j], 0, 0, 0);
        }
    }

    // ---- epilogue: per-row (min, argmin, 2ndmin) over this 128-code tile
    float se[4];
#pragma unroll
    for (int j = 0; j < 4; ++j) se[j] = sume[col0 + 64 * wx + 16 * j + l15];

    __syncthreads();
#pragma unroll
    for (int i = 0; i < 4; ++i) {
#pragma unroll
        for (int reg = 0; reg < 4; ++reg) {
            float v1 = FLT_MAX, v2 = FLT_MAX; int k1 = 0;
#pragma unroll
            for (int j = 0; j < 4; ++j) {
                const float s = __builtin_fmaf(-2.f, acc[i][j][reg], se[j]);
                const int c = col0 + 64 * wx + 16 * j + l15;
                if (s < v1) { v2 = v1; v1 = s; k1 = c; }
                else        { v2 = fminf(v2, s); }
            }
#pragma unroll
            for (int m = 1; m <= 8; m <<= 1) {
                const float ov1 = __shfl_xor(v1, m, 64);
                const int   ok1 = __shfl_xor(k1, m, 64);
                const float ov2 = __shfl_xor(v2, m, 64);
                const float nv2 = fminf(fmaxf(v1, ov1), fminf(v2, ov2));
                if (ov1 < v1) { v1 = ov1; k1 = ok1; }
                v2 = nv2;
            }
            const int rlw = 64 * wy + 16 * i + 4 * q4 + reg;
            if (l15 == 0) { ev1[wx][rlw] = v1; ek1[wx][rlw] = k1; ev2[wx][rlw] = v2; }
        }
    }
    __syncthreads();
    if (tid < 128) {
        const float a1 = ev1[0][tid], b1 = ev1[1][tid];
        const float a2 = ev2[0][tid], b2 = ev2[1][tid];
        const int   ak = ek1[0][tid], bk = ek1[1][tid];
        float gv1, gv2; int gk1;
        if (b1 < a1) { gv1 = b1; gk1 = bk; gv2 = fminf(fminf(a1, a2), b2); }
        else         { gv1 = a1; gk1 = ak; gv2 = fminf(fminf(b1, a2), b2); }
        const size_t o = (size_t)(row0 + tid) * NTILE + nb;
        lmin[o] = gv1; l2nd[o] = gv2; lidx[o] = gk1;
    }
}

// exact rescore of provably-covering candidate set; one wave per row.
// margin = 2*(2^-7*||x||*||e||max + 6.5e-5): bf16-RNE dot error bound + two
// half-ulp(512) roundings in the exact formula, doubled for two-sidedness.
__global__ __launch_bounds__(256) void rescore_kernel(
        const float* __restrict__ x, const float* __restrict__ e,
        const float* __restrict__ sumx, const float* __restrict__ sume,
        const float* __restrict__ semax,
        const float* __restrict__ lmin, const float* __restrict__ l2nd,
        const int* __restrict__ lidx, int* __restrict__ inds) {
    __shared__ float xr[4][DDIM];
    __shared__ int list[4][64];

    const int w = threadIdx.x >> 6, lane = threadIdx.x & 63;
    const int row = blockIdx.x * 4 + w;

    const float lm = lmin[(size_t)row * NTILE + lane];
    const float l2 = l2nd[(size_t)row * NTILE + lane];
    const int   li = lidx[(size_t)row * NTILE + lane];

    float mr = lm;
#pragma unroll
    for (int m = 1; m < 64; m <<= 1) mr = fminf(mr, __shfl_xor(mr, m, 64));

    const float sx  = sumx[row];
    const float thr = mr + (0.0157f * sqrtf(sx) * semax[0] + 1.4e-4f);

    const bool single = (lm <= thr) && (l2 > thr);
    const unsigned long long bs = __ballot(single);
    const int pos = __popcll(bs & ((1ull << lane) - 1ull));
    if (single) list[w][pos] = li;
    const int nS = __popcll(bs);
    unsigned long long bf = __ballot(l2 <= thr);

    {
        const float* px = x + (size_t)row * DDIM + lane * 8;
        *(float4*)(&xr[w][lane * 8])     = *(const float4*)(px);
        *(float4*)(&xr[w][lane * 8 + 4]) = *(const float4*)(px + 4);
    }
    __syncthreads();

    float bd = FLT_MAX; int bk = 0x7fffffff;
    // exact dist: float4 loads, FMA order identical to rounds 1-5
#define EVAL(KK)                                                             \
    {                                                                        \
        const int k_ = (KK);                                                 \
        const float4* ep4 = (const float4*)(e + ((size_t)k_ << 9));          \
        float dot = 0.f;                                                     \
        _Pragma("unroll 4")                                                  \
        for (int d4 = 0; d4 < 128; ++d4) {                                   \
            const float4 ev = ep4[d4];                                       \
            const float4 xv = *(const float4*)(&xr[w][d4 * 4]);              \
            dot = __builtin_fmaf(xv.x, ev.x, dot);                           \
            dot = __builtin_fmaf(xv.y, ev.y, dot);                           \
            dot = __builtin_fmaf(xv.z, ev.z, dot);                           \
            dot = __builtin_fmaf(xv.w, ev.w, dot);                           \
        }                                                                    \
        const float t1   = __fadd_rn(sx, sume[k_]);                          \
        const float dist = __fsub_rn(t1, __fadd_rn(dot, dot));               \
        if (dist < bd || (dist == bd && k_ < bk)) { bd = dist; bk = k_; }    \
    }

    if (lane < nS) EVAL(list[w][lane]);
    while (bf) {
        const int t = __ffsll((long long)bf) - 1;
        bf &= bf - 1;
        EVAL(128 * t + lane);
        EVAL(128 * t + 64 + lane);
    }
#undef EVAL

#pragma unroll
    for (int m = 1; m < 64; m <<= 1) {
        const float od = __shfl_xor(bd, m, 64);
        const int   ok = __shfl_xor(bk, m, 64);
        if (od < bd || (od == bd && ok < bk)) { bd = od; bk = ok; }
    }
    if (lane == 0) inds[row] = bk;
}

// out = x + (e[ind] - x), exact elementwise fp32 STE
__global__ __launch_bounds__(256) void writeout_kernel(const float* __restrict__ x,
                                                       const float* __restrict__ e,
                                                       const int* __restrict__ inds,
                                                       float* __restrict__ out) {
    const int t  = blockIdx.x * blockDim.x + threadIdx.x;
    const int n  = t >> 7;
    const int dq = (t & 127) * 4;
    const int ind = inds[n];
    const float4 xv = *(const float4*)(x + (size_t)n * DDIM + dq);
    const float4 ev = *(const float4*)(e + (size_t)ind * DDIM + dq);
    float4 o;
    o.x = __fadd_rn(xv.x, __fsub_rn(ev.x, xv.x));
    o.y = __fadd_rn(xv.y, __fsub_rn(ev.y, xv.y));
    o.z = __fadd_rn(xv.z, __fsub_rn(ev.z, xv.z));
    o.w = __fadd_rn(xv.w, __fsub_rn(ev.w, xv.w));
    *(float4*)(out + (size_t)n * DDIM + dq) = o;
}

extern "C" void kernel_launch(void* const* d_in, const int* in_sizes, int n_in,
                              void* d_out, int out_size, void* d_ws, size_t ws_size,
                              hipStream_t stream) {
    const float* lat = (const float*)d_in[0];   // (16,2048,512) fp32
    const float* emb = (const float*)d_in[1];   // (8192,512) fp32
    float* out = (float*)d_out;

    char* ws = (char*)d_ws;
    size_t off = 0;
    float*    sume  = (float*)(ws + off);    off += (size_t)KC * 4;
    float*    sumx  = (float*)(ws + off);    off += (size_t)NR * 4;
    float*    semax = (float*)(ws + off);    off += 256;
    float*    lmin  = (float*)(ws + off);    off += (size_t)NR * NTILE * 4;
    float*    l2nd  = (float*)(ws + off);    off += (size_t)NR * NTILE * 4;
    int*      lidx  = (int*)  (ws + off);    off += (size_t)NR * NTILE * 4;
    int*      inds  = (int*)  (ws + off);    off += (size_t)NR * 4;
    unsigned* xb    = (unsigned*)(ws + off); off += (size_t)NR * DDIM * 2;
    unsigned* eb    = (unsigned*)(ws + off); off += (size_t)KC * DDIM * 2;

    cvt_bf16_kernel<<<(NR * DDIM / 8) / 256, 256, 0, stream>>>(lat, xb);
    cvt_bf16_kernel<<<(KC * DDIM / 8) / 256, 256, 0, stream>>>(emb, eb);
    rownorm_kernel<<<KC, 64, 0, stream>>>(emb, sume);
    rownorm_kernel<<<NR, 64, 0, stream>>>(lat, sumx);
    semax_kernel<<<1, 256, 0, stream>>>(sume, semax);
    gemm_filter_kernel<<<(NR / 128) * NTILE, 256, 0, stream>>>(xb, eb, sume, lmin, l2nd, lidx);
    rescore_kernel<<<NR / 4, 256, 0, stream>>>(lat, emb, sumx, sume, semax, lmin, l2nd, lidx, inds);
    writeout_kernel<<<(NR * DDIM / 4) / 256, 256, 0, stream>>>(lat, emb, inds, out);
}

// Round 7
// 806.099 us; speedup vs baseline: 4.9688x; 1.1098x over previous
//
#include <hip/hip_runtime.h>
#include <hip/hip_bf16.h>
#include <float.h>

#define NR    32768
#define DDIM  512
#define KC    8192
#define NTILE 64      // KC / 128 code-tiles

typedef __attribute__((ext_vector_type(8))) short short8;   // 8 bf16 = 4 VGPR
typedef __attribute__((ext_vector_type(4))) float f32x4;
typedef const __attribute__((address_space(1))) char gchar_t;
typedef __attribute__((address_space(3))) char lchar_t;

// pack two fp32 -> two bf16 (RNE) in one u32 (low word = first element)
__device__ inline unsigned cvt2(float a, float b) {
    __hip_bfloat162 h = __float22bfloat162_rn(float2{a, b});
    union { __hip_bfloat162 h; unsigned u; } v; v.h = h;
    return v.u;
}

// fp32 -> bf16 (RNE) pre-conversion, one 16B output granule per thread
__global__ __launch_bounds__(256) void cvt_bf16_kernel(const float* __restrict__ src,
                                                       unsigned* __restrict__ dst) {
    const int t = blockIdx.x * 256 + threadIdx.x;
    const float4 a = *(const float4*)(src + (size_t)t * 8);
    const float4 b = *(const float4*)(src + (size_t)t * 8 + 4);
    uint4 o;
    o.x = cvt2(a.x, a.y); o.y = cvt2(a.z, a.w);
    o.z = cvt2(b.x, b.y); o.w = cvt2(b.z, b.w);
    *(uint4*)(dst + (size_t)t * 4) = o;
}

// sum of squares, one row per 64-thread block. Bitwise-identical to rounds 1-6
// (its rounding is baked into the verified-passing dist values -- DO NOT touch).
__global__ __launch_bounds__(64) void rownorm_kernel(const float* __restrict__ src,
                                                     float* __restrict__ dst) {
    const int row  = blockIdx.x;
    const int lane = threadIdx.x;
    const float* p = src + (size_t)row * DDIM;
    float s = 0.0f;
#pragma unroll
    for (int i = 0; i < DDIM / 64; ++i) {
        float v = p[lane + i * 64];
        s = __builtin_fmaf(v, v, s);
    }
#pragma unroll
    for (int off = 32; off > 0; off >>= 1) s += __shfl_down(s, off, 64);
    if (lane == 0) dst[row] = s;
}

__global__ __launch_bounds__(256) void semax_kernel(const float* __restrict__ sume,
                                                    float* __restrict__ semax) {
    __shared__ float red[256];
    float m = 0.f;
    for (int i = threadIdx.x; i < KC; i += 256) m = fmaxf(m, sume[i]);
    red[threadIdx.x] = m;
    __syncthreads();
    for (int s = 128; s > 0; s >>= 1) {
        if (threadIdx.x < s) red[threadIdx.x] = fmaxf(red[threadIdx.x], red[threadIdx.x + s]);
        __syncthreads();
    }
    if (threadIdx.x == 0) semax[0] = sqrtf(red[0]);
}

// bf16 MFMA approx-score GEMM + per-(row, code-tile) (min, argmin, 2ndmin).
// Round-7 structure: double-buffered LDS (X0|E0|X1|E1, 16 KB each), ONE
// barrier per K-iter; DMA(it+1) issued right after the barrier so its latency
// overlaps compute(it) and the next barrier's vmcnt drain finds it complete.
// DMA pattern (round 6, verified): 8 lanes per row, source octet (L&7)^(L>>3)
// -> 16 fully-used 64B lines/instr; frag ds_read_b128 conflict-free.
// Epilogue: serial j-reduce -> rotation-swizzled LDS partials (reusing the
// dead GEMM buffers) -> 128-thread serial merge (replaces shuffle cascade).
__global__ __launch_bounds__(256) void gemm_filter_kernel(
        const unsigned* __restrict__ xb, const unsigned* __restrict__ eb,
        const float* __restrict__ sume,
        float* __restrict__ lmin, float* __restrict__ l2nd, int* __restrict__ lidx) {
    __shared__ alignas(16) char smem[65536];

    const int tid  = threadIdx.x;
    const int nb   = blockIdx.x & (NTILE - 1);
    const int mb   = blockIdx.x >> 6;
    const int row0 = mb * 128, col0 = nb * 128;
    const int lane = tid & 63, w = tid >> 6;
    const int wy = w >> 1, wx = w & 1;
    const int l15 = lane & 15, q4 = lane >> 4;   // q4 in [0,4)
    const int rl  = lane >> 3;                   // DMA: row within 8-row group
    const int qs  = (lane & 7) ^ rl;             // DMA: permuted source octet

    f32x4 acc[4][4];
#pragma unroll
    for (int i = 0; i < 4; ++i)
#pragma unroll
        for (int j = 0; j < 4; ++j) acc[i][j] = f32x4{0.f, 0.f, 0.f, 0.f};

    // per-thread global byte offsets (d-offset added per iter)
    const size_t xbase[4] = {
        (((size_t)(row0 + (w * 4 + 0) * 8 + rl)) << 10) + (qs << 4),
        (((size_t)(row0 + (w * 4 + 1) * 8 + rl)) << 10) + (qs << 4),
        (((size_t)(row0 + (w * 4 + 2) * 8 + rl)) << 10) + (qs << 4),
        (((size_t)(row0 + (w * 4 + 3) * 8 + rl)) << 10) + (qs << 4) };
    const size_t ebase[4] = {
        (((size_t)(col0 + (w * 4 + 0) * 8 + rl)) << 10) + (qs << 4),
        (((size_t)(col0 + (w * 4 + 1) * 8 + rl)) << 10) + (qs << 4),
        (((size_t)(col0 + (w * 4 + 2) * 8 + rl)) << 10) + (qs << 4),
        (((size_t)(col0 + (w * 4 + 3) * 8 + rl)) << 10) + (qs << 4) };

    // prologue: stage iter 0 into buffer 0
#pragma unroll
    for (int t = 0; t < 4; ++t) {
        __builtin_amdgcn_global_load_lds((gchar_t*)((const char*)xb + xbase[t]),
            (lchar_t*)(smem + (w * 4 + t) * 1024), 16, 0, 0);
        __builtin_amdgcn_global_load_lds((gchar_t*)((const char*)eb + ebase[t]),
            (lchar_t*)(smem + 16384 + (w * 4 + t) * 1024), 16, 0, 0);
    }

    for (int it = 0; it < 8; ++it) {
        const int cur = (it & 1) * 32768;
        __syncthreads();   // drains DMA(it) (issued >=1 compute-phase ago); buf[nxt] free
        if (it < 7) {
            const size_t dbyte = (size_t)(it + 1) * 128;
            const int nxt = 32768 - cur;
#pragma unroll
            for (int t = 0; t < 4; ++t) {
                __builtin_amdgcn_global_load_lds(
                    (gchar_t*)((const char*)xb + xbase[t] + dbyte),
                    (lchar_t*)(smem + nxt + (w * 4 + t) * 1024), 16, 0, 0);
                __builtin_amdgcn_global_load_lds(
                    (gchar_t*)((const char*)eb + ebase[t] + dbyte),
                    (lchar_t*)(smem + nxt + 16384 + (w * 4 + t) * 1024), 16, 0, 0);
            }
        }
        const char* Xc = smem + cur;
        const char* Ec = smem + cur + 16384;
#pragma unroll
        for (int ks = 0; ks < 2; ++ks) {
            short8 A[4], B[4];
            const int qg = ks * 4 + q4;
#pragma unroll
            for (int i = 0; i < 4; ++i) {
                const int ra = 64 * wy + 16 * i + l15;
                A[i] = *(const short8*)(Xc + (ra * 8 + (qg ^ (ra & 7))) * 16);
                const int rb = 64 * wx + 16 * i + l15;
                B[i] = *(const short8*)(Ec + (rb * 8 + (qg ^ (rb & 7))) * 16);
            }
#pragma unroll
            for (int i = 0; i < 4; ++i)
#pragma unroll
                for (int j = 0; j < 4; ++j)
                    acc[i][j] = __builtin_amdgcn_mfma_f32_16x16x32_bf16(A[i], B[j], acc[i][j], 0, 0, 0);
        }
    }

    // ---- epilogue: per-row (min, argmin, 2ndmin) over this 128-code tile
    float se[4];
#pragma unroll
    for (int j = 0; j < 4; ++j) se[j] = sume[col0 + 64 * wx + 16 * j + l15];

    __syncthreads();                       // K-loop fully done; reuse smem as scratch
    float* pv1 = (float*)smem;             // [128][32] partial min
    float* pv2 = (float*)(smem + 16384);   // [128][32] partial 2nd-min
    int*   pk1 = (int*)(smem + 32768);     // [128][32] partial argmin

#pragma unroll
    for (int i = 0; i < 4; ++i) {
#pragma unroll
        for (int reg = 0; reg < 4; ++reg) {
            float v1 = FLT_MAX, v2 = FLT_MAX; int k1 = 0;
#pragma unroll
            for (int j = 0; j < 4; ++j) {
                const float s = __builtin_fmaf(-2.f, acc[i][j][reg], se[j]);
                const int c = col0 + 64 * wx + 16 * j + l15;
                if (s < v1) { v2 = v1; v1 = s; k1 = c; }
                else        { v2 = fminf(v2, s); }
            }
            const int rowl = 64 * wy + 16 * i + 4 * q4 + reg;
            const int slot = rowl * 32 + (((wx * 16 + l15) + rowl) & 31);  // rotation swizzle
            pv1[slot] = v1; pv2[slot] = v2; pk1[slot] = k1;
        }
    }
    __syncthreads();
    if (tid < 128) {
        float g1 = FLT_MAX, g2 = FLT_MAX; int gk = 0;
#pragma unroll 8
        for (int c = 0; c < 32; ++c) {
            const int slot = tid * 32 + ((c + tid) & 31);   // rotated read: conflict-free
            const float p1 = pv1[slot];
            const float p2 = pv2[slot];
            const int   pk = pk1[slot];
            if (p1 < g1) { g2 = fminf(g1, p2); g1 = p1; gk = pk; }
            else         { g2 = fminf(g2, p1); }   // p2 >= p1 >= g1 can't be 2nd
        }
        const size_t o = (size_t)(row0 + tid) * NTILE + nb;
        lmin[o] = g1; l2nd[o] = g2; lidx[o] = gk;
    }
}

// exact rescore of provably-covering candidate set; one wave per row.
// margin = 2*(2^-7*||x||*||e||max + 6.5e-5): bf16-RNE dot error bound + two
// half-ulp(512) roundings in the exact formula, doubled for two-sidedness.
__global__ __launch_bounds__(256) void rescore_kernel(
        const float* __restrict__ x, const float* __restrict__ e,
        const float* __restrict__ sumx, const float* __restrict__ sume,
        const float* __restrict__ semax,
        const float* __restrict__ lmin, const float* __restrict__ l2nd,
        const int* __restrict__ lidx, int* __restrict__ inds) {
    __shared__ float xr[4][DDIM];
    __shared__ int list[4][64];

    const int w = threadIdx.x >> 6, lane = threadIdx.x & 63;
    const int row = blockIdx.x * 4 + w;

    const float lm = lmin[(size_t)row * NTILE + lane];
    const float l2 = l2nd[(size_t)row * NTILE + lane];
    const int   li = lidx[(size_t)row * NTILE + lane];

    float mr = lm;
#pragma unroll
    for (int m = 1; m < 64; m <<= 1) mr = fminf(mr, __shfl_xor(mr, m, 64));

    const float sx  = sumx[row];
    const float thr = mr + (0.0157f * sqrtf(sx) * semax[0] + 1.4e-4f);

    const bool single = (lm <= thr) && (l2 > thr);
    const unsigned long long bs = __ballot(single);
    const int pos = __popcll(bs & ((1ull << lane) - 1ull));
    if (single) list[w][pos] = li;
    const int nS = __popcll(bs);
    unsigned long long bf = __ballot(l2 <= thr);

    {
        const float* px = x + (size_t)row * DDIM + lane * 8;
        *(float4*)(&xr[w][lane * 8])     = *(const float4*)(px);
        *(float4*)(&xr[w][lane * 8 + 4]) = *(const float4*)(px + 4);
    }
    __syncthreads();

    float bd = FLT_MAX; int bk = 0x7fffffff;
    // exact dist: float4 loads, FMA order identical to rounds 1-6
#define EVAL(KK)                                                             \
    {                                                                        \
        const int k_ = (KK);                                                 \
        const float4* ep4 = (const float4*)(e + ((size_t)k_ << 9));          \
        float dot = 0.f;                                                     \
        _Pragma("unroll 4")                                                  \
        for (int d4 = 0; d4 < 128; ++d4) {                                   \
            const float4 ev = ep4[d4];                                       \
            const float4 xv = *(const float4*)(&xr[w][d4 * 4]);              \
            dot = __builtin_fmaf(xv.x, ev.x, dot);                           \
            dot = __builtin_fmaf(xv.y, ev.y, dot);                           \
            dot = __builtin_fmaf(xv.z, ev.z, dot);                           \
            dot = __builtin_fmaf(xv.w, ev.w, dot);                           \
        }                                                                    \
        const float t1   = __fadd_rn(sx, sume[k_]);                          \
        const float dist = __fsub_rn(t1, __fadd_rn(dot, dot));               \
        if (dist < bd || (dist == bd && k_ < bk)) { bd = dist; bk = k_; }    \
    }

    if (lane < nS) EVAL(list[w][lane]);
    while (bf) {
        const int t = __ffsll((long long)bf) - 1;
        bf &= bf - 1;
        EVAL(128 * t + lane);
        EVAL(128 * t + 64 + lane);
    }
#undef EVAL

#pragma unroll
    for (int m = 1; m < 64; m <<= 1) {
        const float od = __shfl_xor(bd, m, 64);
        const int   ok = __shfl_xor(bk, m, 64);
        if (od < bd || (od == bd && ok < bk)) { bd = od; bk = ok; }
    }
    if (lane == 0) inds[row] = bk;
}

// out = x + (e[ind] - x), exact elementwise fp32 STE
__global__ __launch_bounds__(256) void writeout_kernel(const float* __restrict__ x,
                                                       const float* __restrict__ e,
                                                       const int* __restrict__ inds,
                                                       float* __restrict__ out) {
    const int t  = blockIdx.x * blockDim.x + threadIdx.x;
    const int n  = t >> 7;
    const int dq = (t & 127) * 4;
    const int ind = inds[n];
    const float4 xv = *(const float4*)(x + (size_t)n * DDIM + dq);
    const float4 ev = *(const float4*)(e + (size_t)ind * DDIM + dq);
    float4 o;
    o.x = __fadd_rn(xv.x, __fsub_rn(ev.x, xv.x));
    o.y = __fadd_rn(xv.y, __fsub_rn(ev.y, xv.y));
    o.z = __fadd_rn(xv.z, __fsub_rn(ev.z, xv.z));
    o.w = __fadd_rn(xv.w, __fsub_rn(ev.w, xv.w));
    *(float4*)(out + (size_t)n * DDIM + dq) = o;
}

extern "C" void kernel_launch(void* const* d_in, const int* in_sizes, int n_in,
                              void* d_out, int out_size, void* d_ws, size_t ws_size,
                              hipStream_t stream) {
    const float* lat = (const float*)d_in[0];   // (16,2048,512) fp32
    const float* emb = (const float*)d_in[1];   // (8192,512) fp32
    float* out = (float*)d_out;

    char* ws = (char*)d_ws;
    size_t off = 0;
    float*    sume  = (float*)(ws + off);    off += (size_t)KC * 4;
    float*    sumx  = (float*)(ws + off);    off += (size_t)NR * 4;
    float*    semax = (float*)(ws + off);    off += 256;
    float*    lmin  = (float*)(ws + off);    off += (size_t)NR * NTILE * 4;
    float*    l2nd  = (float*)(ws + off);    off += (size_t)NR * NTILE * 4;
    int*      lidx  = (int*)  (ws + off);    off += (size_t)NR * NTILE * 4;
    int*      inds  = (int*)  (ws + off);    off += (size_t)NR * 4;
    unsigned* xb    = (unsigned*)(ws + off); off += (size_t)NR * DDIM * 2;
    unsigned* eb    = (unsigned*)(ws + off); off += (size_t)KC * DDIM * 2;

    cvt_bf16_kernel<<<(NR * DDIM / 8) / 256, 256, 0, stream>>>(lat, xb);
    cvt_bf16_kernel<<<(KC * DDIM / 8) / 256, 256, 0, stream>>>(emb, eb);
    rownorm_kernel<<<KC, 64, 0, stream>>>(emb, sume);
    rownorm_kernel<<<NR, 64, 0, stream>>>(lat, sumx);
    semax_kernel<<<1, 256, 0, stream>>>(sume, semax);
    gemm_filter_kernel<<<(NR / 128) * NTILE, 256, 0, stream>>>(xb, eb, sume, lmin, l2nd, lidx);
    rescore_kernel<<<NR / 4, 256, 0, stream>>>(lat, emb, sumx, sume, semax, lmin, l2nd, lidx, inds);
    writeout_kernel<<<(NR * DDIM / 4) / 256, 256, 0, stream>>>(lat, emb, inds, out);
}

// Round 8
// 754.898 us; speedup vs baseline: 5.3058x; 1.0678x over previous
//
#include <hip/hip_runtime.h>
#include <hip/hip_bf16.h>
#include <float.h>

#define NR    32768
#define DDIM  512
#define KC    8192
#define NTILE 64      // KC / 128 code-tiles

typedef __attribute__((ext_vector_type(8))) short short8;   // 8 bf16 = 4 VGPR
typedef __attribute__((ext_vector_type(4))) float f32x4;
typedef const __attribute__((address_space(1))) char gchar_t;
typedef __attribute__((address_space(3))) char lchar_t;

// pack two fp32 -> two bf16 (RNE) in one u32 (low word = first element)
__device__ inline unsigned cvt2(float a, float b) {
    __hip_bfloat162 h = __float22bfloat162_rn(float2{a, b});
    union { __hip_bfloat162 h; unsigned u; } v; v.h = h;
    return v.u;
}

// fp32 -> bf16 (RNE) pre-conversion, one 16B output granule per thread
__global__ __launch_bounds__(256) void cvt_bf16_kernel(const float* __restrict__ src,
                                                       unsigned* __restrict__ dst) {
    const int t = blockIdx.x * 256 + threadIdx.x;
    const float4 a = *(const float4*)(src + (size_t)t * 8);
    const float4 b = *(const float4*)(src + (size_t)t * 8 + 4);
    uint4 o;
    o.x = cvt2(a.x, a.y); o.y = cvt2(a.z, a.w);
    o.z = cvt2(b.x, b.y); o.w = cvt2(b.z, b.w);
    *(uint4*)(dst + (size_t)t * 4) = o;
}

// sum of squares, one row per 64-thread block. Bitwise-identical to rounds 1-7
// (its rounding is baked into the verified-passing dist values -- DO NOT touch).
__global__ __launch_bounds__(64) void rownorm_kernel(const float* __restrict__ src,
                                                     float* __restrict__ dst) {
    const int row  = blockIdx.x;
    const int lane = threadIdx.x;
    const float* p = src + (size_t)row * DDIM;
    float s = 0.0f;
#pragma unroll
    for (int i = 0; i < DDIM / 64; ++i) {
        float v = p[lane + i * 64];
        s = __builtin_fmaf(v, v, s);
    }
#pragma unroll
    for (int off = 32; off > 0; off >>= 1) s += __shfl_down(s, off, 64);
    if (lane == 0) dst[row] = s;
}

__global__ __launch_bounds__(256) void semax_kernel(const float* __restrict__ sume,
                                                    float* __restrict__ semax) {
    __shared__ float red[256];
    float m = 0.f;
    for (int i = threadIdx.x; i < KC; i += 256) m = fmaxf(m, sume[i]);
    red[threadIdx.x] = m;
    __syncthreads();
    for (int s = 128; s > 0; s >>= 1) {
        if (threadIdx.x < s) red[threadIdx.x] = fmaxf(red[threadIdx.x], red[threadIdx.x + s]);
        __syncthreads();
    }
    if (threadIdx.x == 0) semax[0] = sqrtf(red[0]);
}

// bf16 MFMA approx-score GEMM + per-(row, code-tile) (min, argmin, 2ndmin).
// Round-8 structure: BK=32, double-buffered (2 x 16 KB = 32 KB LDS -> 4-5
// blocks/CU for TLP stall-filling), one barrier/iter, fully unrolled K-loop.
// DMA mapping: 4 lanes/row x 64-B row-chunk, source octet (L&3)^((L>>2)&3)
// -> 16 fully-used 64B lines/instr. Implied LDS layout: octet q of row r at
// 16B-slot r*4 + (q ^ (r&3)). Fragment read byte offset reduces to the
// loop-invariant (64*wv + l15)*64 + ((q4^(l15&3))<<4) + i*1024 -> one base
// VGPR + immediate per ds_read_b128, bank-uniform (32 B/bank per instr).
// K-chunk accumulation order identical to rounds 5-7 (bit-exact scores).
__global__ __launch_bounds__(256) void gemm_filter_kernel(
        const unsigned* __restrict__ xb, const unsigned* __restrict__ eb,
        const float* __restrict__ sume,
        float* __restrict__ lmin, float* __restrict__ l2nd, int* __restrict__ lidx) {
    __shared__ alignas(16) char smem[32768];   // 2 x (X 8 KB | E 8 KB)

    const int tid  = threadIdx.x;
    const int nb   = blockIdx.x & (NTILE - 1);
    const int mb   = blockIdx.x >> 6;
    const int row0 = mb * 128, col0 = nb * 128;
    const int lane = tid & 63, w = tid >> 6;
    const int wy = w >> 1, wx = w & 1;
    const int l15 = lane & 15, q4 = lane >> 4;   // q4 in [0,4)
    const int drow = lane >> 2;                  // DMA: row within 16-row group
    const int doct = (lane & 3) ^ (drow & 3);    // DMA: permuted source octet

    f32x4 acc[4][4];
#pragma unroll
    for (int i = 0; i < 4; ++i)
#pragma unroll
        for (int j = 0; j < 4; ++j) acc[i][j] = f32x4{0.f, 0.f, 0.f, 0.f};

    // global base addresses for this thread's two X-DMAs and two E-DMAs
    const char* xg[2], * eg[2];
#pragma unroll
    for (int t = 0; t < 2; ++t) {
        xg[t] = (const char*)xb + (((size_t)(row0 + (w * 2 + t) * 16 + drow)) << 10) + (doct << 4);
        eg[t] = (const char*)eb + (((size_t)(col0 + (w * 2 + t) * 16 + drow)) << 10) + (doct << 4);
    }
    // loop-invariant fragment byte offsets (ra&3 == l15&3 since 64wy+16i = 0 mod 4)
    const int aoff = (64 * wy + l15) * 64 + ((q4 ^ (l15 & 3)) << 4);  // + i*1024
    const int boff = (64 * wx + l15) * 64 + ((q4 ^ (l15 & 3)) << 4);  // + j*1024

    // prologue: stage iter 0 into buffer 0
#pragma unroll
    for (int t = 0; t < 2; ++t) {
        __builtin_amdgcn_global_load_lds((gchar_t*)xg[t],
            (lchar_t*)(smem + (w * 2 + t) * 1024), 16, 0, 0);
        __builtin_amdgcn_global_load_lds((gchar_t*)eg[t],
            (lchar_t*)(smem + 8192 + (w * 2 + t) * 1024), 16, 0, 0);
    }

#pragma unroll
    for (int it = 0; it < 16; ++it) {
        const int cur = (it & 1) * 16384;
        __syncthreads();   // drains DMA(it); buffer[nxt] free for overwrite
        if (it < 15) {
            const int nxt = 16384 - cur;
            const int db = (it + 1) * 64;     // unrolled -> folds into addressing
#pragma unroll
            for (int t = 0; t < 2; ++t) {
                __builtin_amdgcn_global_load_lds((gchar_t*)(xg[t] + db),
                    (lchar_t*)(smem + nxt + (w * 2 + t) * 1024), 16, 0, 0);
                __builtin_amdgcn_global_load_lds((gchar_t*)(eg[t] + db),
                    (lchar_t*)(smem + nxt + 8192 + (w * 2 + t) * 1024), 16, 0, 0);
            }
        }
        const char* Xc = smem + cur;
        const char* Ec = smem + cur + 8192;
        short8 A[4], B[4];
#pragma unroll
        for (int i = 0; i < 4; ++i) A[i] = *(const short8*)(Xc + aoff + i * 1024);
#pragma unroll
        for (int j = 0; j < 4; ++j) B[j] = *(const short8*)(Ec + boff + j * 1024);
#pragma unroll
        for (int i = 0; i < 4; ++i)
#pragma unroll
            for (int j = 0; j < 4; ++j)
                acc[i][j] = __builtin_amdgcn_mfma_f32_16x16x32_bf16(A[i], B[j], acc[i][j], 0, 0, 0);
    }

    // ---- epilogue: per-row (min, argmin, 2ndmin) over this 128-code tile.
    // Partials pre-reduced 4:1 via two shuffle-xor steps, then 12 KB LDS
    // scratch (reusing buffer-0 region; last compute reads were from buf 1).
    float se[4];
#pragma unroll
    for (int j = 0; j < 4; ++j) se[j] = sume[col0 + 64 * wx + 16 * j + l15];

    float* pv1 = (float*)smem;             // [128][8]
    float* pv2 = (float*)(smem + 4096);    // [128][8]
    int*   pk1 = (int*)(smem + 8192);      // [128][8]

#pragma unroll
    for (int i = 0; i < 4; ++i) {
#pragma unroll
        for (int reg = 0; reg < 4; ++reg) {
            float v1 = FLT_MAX, v2 = FLT_MAX; int k1 = 0;
#pragma unroll
            for (int j = 0; j < 4; ++j) {
                const float s = __builtin_fmaf(-2.f, acc[i][j][reg], se[j]);
                const int c = col0 + 64 * wx + 16 * j + l15;
                if (s < v1) { v2 = v1; v1 = s; k1 = c; }
                else        { v2 = fminf(v2, s); }
            }
            // merge groups of 4 l15-lanes (exact ties leave l2nd==lmin -> the
            // rescore full-scans the tile, so tie-side argmin choice is moot)
#pragma unroll
            for (int m = 1; m <= 2; m <<= 1) {
                const float ov1 = __shfl_xor(v1, m, 64);
                const int   ok1 = __shfl_xor(k1, m, 64);
                const float ov2 = __shfl_xor(v2, m, 64);
                const float nv2 = fminf(fmaxf(v1, ov1), fminf(v2, ov2));
                if (ov1 < v1) { v1 = ov1; k1 = ok1; }
                v2 = nv2;
            }
            if ((l15 & 3) == 0) {
                const int rowl = 64 * wy + 16 * i + 4 * q4 + reg;
                const int c8   = wx * 4 + (l15 >> 2);
                const int slot = rowl * 8 + ((c8 + rowl) & 7);   // rotation swizzle
                pv1[slot] = v1; pv2[slot] = v2; pk1[slot] = k1;
            }
        }
    }
    __syncthreads();
    if (tid < 128) {
        float g1 = FLT_MAX, g2 = FLT_MAX; int gk = 0;
#pragma unroll
        for (int c = 0; c < 8; ++c) {
            const int slot = tid * 8 + ((c + tid) & 7);
            const float p1 = pv1[slot];
            const float p2 = pv2[slot];
            const int   pk = pk1[slot];
            if (p1 < g1) { g2 = fminf(g1, p2); g1 = p1; gk = pk; }
            else         { g2 = fminf(g2, p1); }
        }
        const size_t o = (size_t)(row0 + tid) * NTILE + nb;
        lmin[o] = g1; l2nd[o] = g2; lidx[o] = gk;
    }
}

// exact rescore of provably-covering candidate set; one wave per row.
// margin = 2*(2^-7*||x||*||e||max + 6.5e-5): bf16-RNE dot error bound + two
// half-ulp(512) roundings in the exact formula, doubled for two-sidedness.
__global__ __launch_bounds__(256) void rescore_kernel(
        const float* __restrict__ x, const float* __restrict__ e,
        const float* __restrict__ sumx, const float* __restrict__ sume,
        const float* __restrict__ semax,
        const float* __restrict__ lmin, const float* __restrict__ l2nd,
        const int* __restrict__ lidx, int* __restrict__ inds) {
    __shared__ float xr[4][DDIM];
    __shared__ int list[4][64];

    const int w = threadIdx.x >> 6, lane = threadIdx.x & 63;
    const int row = blockIdx.x * 4 + w;

    const float lm = lmin[(size_t)row * NTILE + lane];
    const float l2 = l2nd[(size_t)row * NTILE + lane];
    const int   li = lidx[(size_t)row * NTILE + lane];

    float mr = lm;
#pragma unroll
    for (int m = 1; m < 64; m <<= 1) mr = fminf(mr, __shfl_xor(mr, m, 64));

    const float sx  = sumx[row];
    const float thr = mr + (0.0157f * sqrtf(sx) * semax[0] + 1.4e-4f);

    const bool single = (lm <= thr) && (l2 > thr);
    const unsigned long long bs = __ballot(single);
    const int pos = __popcll(bs & ((1ull << lane) - 1ull));
    if (single) list[w][pos] = li;
    const int nS = __popcll(bs);
    unsigned long long bf = __ballot(l2 <= thr);

    {
        const float* px = x + (size_t)row * DDIM + lane * 8;
        *(float4*)(&xr[w][lane * 8])     = *(const float4*)(px);
        *(float4*)(&xr[w][lane * 8 + 4]) = *(const float4*)(px + 4);
    }
    __syncthreads();

    float bd = FLT_MAX; int bk = 0x7fffffff;
    // exact dist: float4 loads, FMA order identical to rounds 1-7
#define EVAL(KK)                                                             \
    {                                                                        \
        const int k_ = (KK);                                                 \
        const float4* ep4 = (const float4*)(e + ((size_t)k_ << 9));          \
        float dot = 0.f;                                                     \
        _Pragma("unroll 4")                                                  \
        for (int d4 = 0; d4 < 128; ++d4) {                                   \
            const float4 ev = ep4[d4];                                       \
            const float4 xv = *(const float4*)(&xr[w][d4 * 4]);              \
            dot = __builtin_fmaf(xv.x, ev.x, dot);                           \
            dot = __builtin_fmaf(xv.y, ev.y, dot);                           \
            dot = __builtin_fmaf(xv.z, ev.z, dot);                           \
            dot = __builtin_fmaf(xv.w, ev.w, dot);                           \
        }                                                                    \
        const float t1   = __fadd_rn(sx, sume[k_]);                          \
        const float dist = __fsub_rn(t1, __fadd_rn(dot, dot));               \
        if (dist < bd || (dist == bd && k_ < bk)) { bd = dist; bk = k_; }    \
    }

    if (lane < nS) EVAL(list[w][lane]);
    while (bf) {
        const int t = __ffsll((long long)bf) - 1;
        bf &= bf - 1;
        EVAL(128 * t + lane);
        EVAL(128 * t + 64 + lane);
    }
#undef EVAL

#pragma unroll
    for (int m = 1; m < 64; m <<= 1) {
        const float od = __shfl_xor(bd, m, 64);
        const int   ok = __shfl_xor(bk, m, 64);
        if (od < bd || (od == bd && ok < bk)) { bd = od; bk = ok; }
    }
    if (lane == 0) inds[row] = bk;
}

// out = x + (e[ind] - x), exact elementwise fp32 STE
__global__ __launch_bounds__(256) void writeout_kernel(const float* __restrict__ x,
                                                       const float* __restrict__ e,
                                                       const int* __restrict__ inds,
                                                       float* __restrict__ out) {
    const int t  = blockIdx.x * blockDim.x + threadIdx.x;
    const int n  = t >> 7;
    const int dq = (t & 127) * 4;
    const int ind = inds[n];
    const float4 xv = *(const float4*)(x + (size_t)n * DDIM + dq);
    const float4 ev = *(const float4*)(e + (size_t)ind * DDIM + dq);
    float4 o;
    o.x = __fadd_rn(xv.x, __fsub_rn(ev.x, xv.x));
    o.y = __fadd_rn(xv.y, __fsub_rn(ev.y, xv.y));
    o.z = __fadd_rn(xv.z, __fsub_rn(ev.z, xv.z));
    o.w = __fadd_rn(xv.w, __fsub_rn(ev.w, xv.w));
    *(float4*)(out + (size_t)n * DDIM + dq) = o;
}

extern "C" void kernel_launch(void* const* d_in, const int* in_sizes, int n_in,
                              void* d_out, int out_size, void* d_ws, size_t ws_size,
                              hipStream_t stream) {
    const float* lat = (const float*)d_in[0];   // (16,2048,512) fp32
    const float* emb = (const float*)d_in[1];   // (8192,512) fp32
    float* out = (float*)d_out;

    char* ws = (char*)d_ws;
    size_t off = 0;
    float*    sume  = (float*)(ws + off);    off += (size_t)KC * 4;
    float*    sumx  = (float*)(ws + off);    off += (size_t)NR * 4;
    float*    semax = (float*)(ws + off);    off += 256;
    float*    lmin  = (float*)(ws + off);    off += (size_t)NR * NTILE * 4;
    float*    l2nd  = (float*)(ws + off);    off += (size_t)NR * NTILE * 4;
    int*      lidx  = (int*)  (ws + off);    off += (size_t)NR * NTILE * 4;
    int*      inds  = (int*)  (ws + off);    off += (size_t)NR * 4;
    unsigned* xb    = (unsigned*)(ws + off); off += (size_t)NR * DDIM * 2;
    unsigned* eb    = (unsigned*)(ws + off); off += (size_t)KC * DDIM * 2;

    cvt_bf16_kernel<<<(NR * DDIM / 8) / 256, 256, 0, stream>>>(lat, xb);
    cvt_bf16_kernel<<<(KC * DDIM / 8) / 256, 256, 0, stream>>>(emb, eb);
    rownorm_kernel<<<KC, 64, 0, stream>>>(emb, sume);
    rownorm_kernel<<<NR, 64, 0, stream>>>(lat, sumx);
    semax_kernel<<<1, 256, 0, stream>>>(sume, semax);
    gemm_filter_kernel<<<(NR / 128) * NTILE, 256, 0, stream>>>(xb, eb, sume, lmin, l2nd, lidx);
    rescore_kernel<<<NR / 4, 256, 0, stream>>>(lat, emb, sumx, sume, semax, lmin, l2nd, lidx, inds);
    writeout_kernel<<<(NR * DDIM / 4) / 256, 256, 0, stream>>>(lat, emb, inds, out);
}

// Round 9
// 735.655 us; speedup vs baseline: 5.4446x; 1.0262x over previous
//
#include <hip/hip_runtime.h>
#include <hip/hip_bf16.h>
#include <float.h>

#define NR    32768
#define DDIM  512
#define KC    8192
#define NTILE 64      // KC / 128 code-tiles

typedef __attribute__((ext_vector_type(8))) short short8;   // 8 bf16 = 4 VGPR
typedef __attribute__((ext_vector_type(4))) float f32x4;
typedef const __attribute__((address_space(1))) char gchar_t;
typedef __attribute__((address_space(3))) char lchar_t;

// pack two fp32 -> two bf16 (RNE) in one u32 (low word = first element)
__device__ inline unsigned cvt2(float a, float b) {
    __hip_bfloat162 h = __float22bfloat162_rn(float2{a, b});
    union { __hip_bfloat162 h; unsigned u; } v; v.h = h;
    return v.u;
}

// fp32 -> bf16 (RNE) row-major, one 16B granule per thread (for X)
__global__ __launch_bounds__(256) void cvt_bf16_kernel(const float* __restrict__ src,
                                                       unsigned* __restrict__ dst) {
    const int t = blockIdx.x * 256 + threadIdx.x;
    const float4 a = *(const float4*)(src + (size_t)t * 8);
    const float4 b = *(const float4*)(src + (size_t)t * 8 + 4);
    uint4 o;
    o.x = cvt2(a.x, a.y); o.y = cvt2(a.z, a.w);
    o.z = cvt2(b.x, b.y); o.w = cvt2(b.z, b.w);
    *(uint4*)(dst + (size_t)t * 4) = o;
}

// fp32 codebook -> bf16 in fragment-major (octet-transposed) order:
// granule (g, k) of row k stored at ebT[(g*KC + k)*16B]. Coalesced writes;
// scattered reads absorbed by L2/L3 (one-time 8 MB transform).
__global__ __launch_bounds__(256) void cvt_ebT_kernel(const float* __restrict__ src,
                                                      unsigned* __restrict__ dst) {
    const int o = blockIdx.x * 256 + threadIdx.x;   // output granule index
    const int k = o & (KC - 1);
    const int g = o >> 13;                          // KC = 8192
    const float* p = src + (size_t)k * DDIM + g * 8;
    const float4 a = *(const float4*)p;
    const float4 b = *(const float4*)(p + 4);
    uint4 v;
    v.x = cvt2(a.x, a.y); v.y = cvt2(a.z, a.w);
    v.z = cvt2(b.x, b.y); v.w = cvt2(b.z, b.w);
    *(uint4*)(dst + (size_t)o * 4) = v;
}

// sum of squares, one row per 64-thread block. Bitwise-identical to rounds 1-8
// (its rounding is baked into the verified-passing dist values -- DO NOT touch).
__global__ __launch_bounds__(64) void rownorm_kernel(const float* __restrict__ src,
                                                     float* __restrict__ dst) {
    const int row  = blockIdx.x;
    const int lane = threadIdx.x;
    const float* p = src + (size_t)row * DDIM;
    float s = 0.0f;
#pragma unroll
    for (int i = 0; i < DDIM / 64; ++i) {
        float v = p[lane + i * 64];
        s = __builtin_fmaf(v, v, s);
    }
#pragma unroll
    for (int off = 32; off > 0; off >>= 1) s += __shfl_down(s, off, 64);
    if (lane == 0) dst[row] = s;
}

__global__ __launch_bounds__(256) void semax_kernel(const float* __restrict__ sume,
                                                    float* __restrict__ semax) {
    __shared__ float red[256];
    float m = 0.f;
    for (int i = threadIdx.x; i < KC; i += 256) m = fmaxf(m, sume[i]);
    red[threadIdx.x] = m;
    __syncthreads();
    for (int s = 128; s > 0; s >>= 1) {
        if (threadIdx.x < s) red[threadIdx.x] = fmaxf(red[threadIdx.x], red[threadIdx.x + s]);
        __syncthreads();
    }
    if (threadIdx.x == 0) semax[0] = sqrtf(red[0]);
}

// bf16 MFMA approx-score GEMM + per-(row, code-tile) (min, argmin, 2ndmin).
// Round-9 structure: E removed from LDS entirely -- B-fragments load as
// coalesced global dwordx4 from octet-transposed ebT, register-double-
// buffered one iter ahead (loads stay in flight across the barrier; the
// barrier's vmcnt(0) finds them complete). X keeps round-8 DMA staging
// (BK=32, double-buffered 2 x 8 KB). LDS-pipe traffic halves vs round 8 --
// that pipe was the binding resource (400 us pin across two structures).
__global__ __launch_bounds__(256) void gemm_filter_kernel(
        const unsigned* __restrict__ xb, const unsigned* __restrict__ ebT,
        const float* __restrict__ sume,
        float* __restrict__ lmin, float* __restrict__ l2nd, int* __restrict__ lidx) {
    __shared__ alignas(16) char smem[16384];   // X dbuf 2 x 8 KB; epilogue scratch overlay

    const int tid  = threadIdx.x;
    const int nb   = blockIdx.x & (NTILE - 1);
    const int mb   = blockIdx.x >> 6;
    const int row0 = mb * 128, col0 = nb * 128;
    const int lane = tid & 63, w = tid >> 6;
    const int wy = w >> 1, wx = w & 1;
    const int l15 = lane & 15, q4 = lane >> 4;   // q4 in [0,4)
    const int drow = lane >> 2;                  // X-DMA: row within 16-row group
    const int doct = (lane & 3) ^ (drow & 3);    // X-DMA: permuted source octet

    f32x4 acc[4][4];
#pragma unroll
    for (int i = 0; i < 4; ++i)
#pragma unroll
        for (int j = 0; j < 4; ++j) acc[i][j] = f32x4{0.f, 0.f, 0.f, 0.f};

    // X-DMA global bases (two 16-row groups per wave)
    const char* xg[2];
#pragma unroll
    for (int t = 0; t < 2; ++t)
        xg[t] = (const char*)xb + (((size_t)(row0 + (w * 2 + t) * 16 + drow)) << 10) + (doct << 4);
    // loop-invariant A-fragment byte offset (ra&3 == l15&3)
    const int aoff = (64 * wy + l15) * 64 + ((q4 ^ (l15 & 3)) << 4);  // + i*1024

    // B global base: granule (g = q4, col = col0 + 64wx + l15), u32 units
    const unsigned* bptr = ebT + ((size_t)(q4 * KC + col0 + 64 * wx + l15)) * 4;
    // j-stride: 16 cols = 16 granules = 64 u32; it-stride: 4*KC granules = 131072 u32

    // prologue: stage X(0); load B(0)
#pragma unroll
    for (int t = 0; t < 2; ++t)
        __builtin_amdgcn_global_load_lds((gchar_t*)xg[t],
            (lchar_t*)(smem + (w * 2 + t) * 1024), 16, 0, 0);
    short8 Bc[4], Bn[4];
#pragma unroll
    for (int j = 0; j < 4; ++j) Bc[j] = *(const short8*)(bptr + j * 64);

#pragma unroll
    for (int it = 0; it < 16; ++it) {
        const int cur = (it & 1) * 8192;
        __syncthreads();   // drains X-DMA(it); B(it) loaded >=1 iter ago
        if (it < 15) {
            const int nxt = 8192 - cur;
            const int db = (it + 1) * 64;
#pragma unroll
            for (int t = 0; t < 2; ++t)
                __builtin_amdgcn_global_load_lds((gchar_t*)(xg[t] + db),
                    (lchar_t*)(smem + nxt + (w * 2 + t) * 1024), 16, 0, 0);
            const unsigned* bn = bptr + (size_t)(it + 1) * 131072;
#pragma unroll
            for (int j = 0; j < 4; ++j) Bn[j] = *(const short8*)(bn + j * 64);
        }
        const char* Xc = smem + cur;
        short8 A[4];
#pragma unroll
        for (int i = 0; i < 4; ++i) A[i] = *(const short8*)(Xc + aoff + i * 1024);
#pragma unroll
        for (int i = 0; i < 4; ++i)
#pragma unroll
            for (int j = 0; j < 4; ++j)
                acc[i][j] = __builtin_amdgcn_mfma_f32_16x16x32_bf16(A[i], Bc[j], acc[i][j], 0, 0, 0);
#pragma unroll
        for (int j = 0; j < 4; ++j) Bc[j] = Bn[j];
    }

    // ---- epilogue: per-row (min, argmin, 2ndmin) over this 128-code tile.
    float se[4];
#pragma unroll
    for (int j = 0; j < 4; ++j) se[j] = sume[col0 + 64 * wx + 16 * j + l15];

    __syncthreads();   // all waves done reading buf1 before scratch overlays it
    float* pv1 = (float*)smem;             // [128][8]
    float* pv2 = (float*)(smem + 4096);    // [128][8]
    int*   pk1 = (int*)(smem + 8192);      // [128][8]

#pragma unroll
    for (int i = 0; i < 4; ++i) {
#pragma unroll
        for (int reg = 0; reg < 4; ++reg) {
            float v1 = FLT_MAX, v2 = FLT_MAX; int k1 = 0;
#pragma unroll
            for (int j = 0; j < 4; ++j) {
                const float s = __builtin_fmaf(-2.f, acc[i][j][reg], se[j]);
                const int c = col0 + 64 * wx + 16 * j + l15;
                if (s < v1) { v2 = v1; v1 = s; k1 = c; }
                else        { v2 = fminf(v2, s); }
            }
            // merge groups of 4 l15-lanes (exact ties leave l2nd==lmin -> the
            // rescore full-scans the tile, so tie-side argmin choice is moot)
#pragma unroll
            for (int m = 1; m <= 2; m <<= 1) {
                const float ov1 = __shfl_xor(v1, m, 64);
                const int   ok1 = __shfl_xor(k1, m, 64);
                const float ov2 = __shfl_xor(v2, m, 64);
                const float nv2 = fminf(fmaxf(v1, ov1), fminf(v2, ov2));
                if (ov1 < v1) { v1 = ov1; k1 = ok1; }
                v2 = nv2;
            }
            if ((l15 & 3) == 0) {
                const int rowl = 64 * wy + 16 * i + 4 * q4 + reg;
                const int c8   = wx * 4 + (l15 >> 2);
                const int slot = rowl * 8 + ((c8 + rowl) & 7);   // rotation swizzle
                pv1[slot] = v1; pv2[slot] = v2; pk1[slot] = k1;
            }
        }
    }
    __syncthreads();
    if (tid < 128) {
        float g1 = FLT_MAX, g2 = FLT_MAX; int gk = 0;
#pragma unroll
        for (int c = 0; c < 8; ++c) {
            const int slot = tid * 8 + ((c + tid) & 7);
            const float p1 = pv1[slot];
            const float p2 = pv2[slot];
            const int   pk = pk1[slot];
            if (p1 < g1) { g2 = fminf(g1, p2); g1 = p1; gk = pk; }
            else         { g2 = fminf(g2, p1); }
        }
        const size_t o = (size_t)(row0 + tid) * NTILE + nb;
        lmin[o] = g1; l2nd[o] = g2; lidx[o] = gk;
    }
}

// exact rescore of provably-covering candidate set; one wave per row.
// margin = 2*(2^-7*||x||*||e||max + 6.5e-5): bf16-RNE dot error bound + two
// half-ulp(512) roundings in the exact formula, doubled for two-sidedness.
__global__ __launch_bounds__(256) void rescore_kernel(
        const float* __restrict__ x, const float* __restrict__ e,
        const float* __restrict__ sumx, const float* __restrict__ sume,
        const float* __restrict__ semax,
        const float* __restrict__ lmin, const float* __restrict__ l2nd,
        const int* __restrict__ lidx, int* __restrict__ inds) {
    __shared__ float xr[4][DDIM];
    __shared__ int list[4][64];

    const int w = threadIdx.x >> 6, lane = threadIdx.x & 63;
    const int row = blockIdx.x * 4 + w;

    const float lm = lmin[(size_t)row * NTILE + lane];
    const float l2 = l2nd[(size_t)row * NTILE + lane];
    const int   li = lidx[(size_t)row * NTILE + lane];

    float mr = lm;
#pragma unroll
    for (int m = 1; m < 64; m <<= 1) mr = fminf(mr, __shfl_xor(mr, m, 64));

    const float sx  = sumx[row];
    const float thr = mr + (0.0157f * sqrtf(sx) * semax[0] + 1.4e-4f);

    const bool single = (lm <= thr) && (l2 > thr);
    const unsigned long long bs = __ballot(single);
    const int pos = __popcll(bs & ((1ull << lane) - 1ull));
    if (single) list[w][pos] = li;
    const int nS = __popcll(bs);
    unsigned long long bf = __ballot(l2 <= thr);

    {
        const float* px = x + (size_t)row * DDIM + lane * 8;
        *(float4*)(&xr[w][lane * 8])     = *(const float4*)(px);
        *(float4*)(&xr[w][lane * 8 + 4]) = *(const float4*)(px + 4);
    }
    __syncthreads();

    float bd = FLT_MAX; int bk = 0x7fffffff;
    // exact dist: float4 loads, FMA order identical to rounds 1-8
#define EVAL(KK)                                                             \
    {                                                                        \
        const int k_ = (KK);                                                 \
        const float4* ep4 = (const float4*)(e + ((size_t)k_ << 9));          \
        float dot = 0.f;                                                     \
        _Pragma("unroll 4")                                                  \
        for (int d4 = 0; d4 < 128; ++d4) {                                   \
            const float4 ev = ep4[d4];                                       \
            const float4 xv = *(const float4*)(&xr[w][d4 * 4]);              \
            dot = __builtin_fmaf(xv.x, ev.x, dot);                           \
            dot = __builtin_fmaf(xv.y, ev.y, dot);                           \
            dot = __builtin_fmaf(xv.z, ev.z, dot);                           \
            dot = __builtin_fmaf(xv.w, ev.w, dot);                           \
        }                                                                    \
        const float t1   = __fadd_rn(sx, sume[k_]);                          \
        const float dist = __fsub_rn(t1, __fadd_rn(dot, dot));               \
        if (dist < bd || (dist == bd && k_ < bk)) { bd = dist; bk = k_; }    \
    }

    if (lane < nS) EVAL(list[w][lane]);
    while (bf) {
        const int t = __ffsll((long long)bf) - 1;
        bf &= bf - 1;
        EVAL(128 * t + lane);
        EVAL(128 * t + 64 + lane);
    }
#undef EVAL

#pragma unroll
    for (int m = 1; m < 64; m <<= 1) {
        const float od = __shfl_xor(bd, m, 64);
        const int   ok = __shfl_xor(bk, m, 64);
        if (od < bd || (od == bd && ok < bk)) { bd = od; bk = ok; }
    }
    if (lane == 0) inds[row] = bk;
}

// out = x + (e[ind] - x), exact elementwise fp32 STE
__global__ __launch_bounds__(256) void writeout_kernel(const float* __restrict__ x,
                                                       const float* __restrict__ e,
                                                       const int* __restrict__ inds,
                                                       float* __restrict__ out) {
    const int t  = blockIdx.x * blockDim.x + threadIdx.x;
    const int n  = t >> 7;
    const int dq = (t & 127) * 4;
    const int ind = inds[n];
    const float4 xv = *(const float4*)(x + (size_t)n * DDIM + dq);
    const float4 ev = *(const float4*)(e + (size_t)ind * DDIM + dq);
    float4 o;
    o.x = __fadd_rn(xv.x, __fsub_rn(ev.x, xv.x));
    o.y = __fadd_rn(xv.y, __fsub_rn(ev.y, xv.y));
    o.z = __fadd_rn(xv.z, __fsub_rn(ev.z, xv.z));
    o.w = __fadd_rn(xv.w, __fsub_rn(ev.w, xv.w));
    *(float4*)(out + (size_t)n * DDIM + dq) = o;
}

extern "C" void kernel_launch(void* const* d_in, const int* in_sizes, int n_in,
                              void* d_out, int out_size, void* d_ws, size_t ws_size,
                              hipStream_t stream) {
    const float* lat = (const float*)d_in[0];   // (16,2048,512) fp32
    const float* emb = (const float*)d_in[1];   // (8192,512) fp32
    float* out = (float*)d_out;

    char* ws = (char*)d_ws;
    size_t off = 0;
    float*    sume  = (float*)(ws + off);    off += (size_t)KC * 4;
    float*    sumx  = (float*)(ws + off);    off += (size_t)NR * 4;
    float*    semax = (float*)(ws + off);    off += 256;
    float*    lmin  = (float*)(ws + off);    off += (size_t)NR * NTILE * 4;
    float*    l2nd  = (float*)(ws + off);    off += (size_t)NR * NTILE * 4;
    int*      lidx  = (int*)  (ws + off);    off += (size_t)NR * NTILE * 4;
    int*      inds  = (int*)  (ws + off);    off += (size_t)NR * 4;
    unsigned* xb    = (unsigned*)(ws + off); off += (size_t)NR * DDIM * 2;
    unsigned* ebT   = (unsigned*)(ws + off); off += (size_t)KC * DDIM * 2;

    cvt_bf16_kernel<<<(NR * DDIM / 8) / 256, 256, 0, stream>>>(lat, xb);
    cvt_ebT_kernel<<<(KC * DDIM / 8) / 256, 256, 0, stream>>>(emb, ebT);
    rownorm_kernel<<<KC, 64, 0, stream>>>(emb, sume);
    rownorm_kernel<<<NR, 64, 0, stream>>>(lat, sumx);
    semax_kernel<<<1, 256, 0, stream>>>(sume, semax);
    gemm_filter_kernel<<<(NR / 128) * NTILE, 256, 0, stream>>>(xb, ebT, sume, lmin, l2nd, lidx);
    rescore_kernel<<<NR / 4, 256, 0, stream>>>(lat, emb, sumx, sume, semax, lmin, l2nd, lidx, inds);
    writeout_kernel<<<(NR * DDIM / 4) / 256, 256, 0, stream>>>(lat, emb, inds, out);
}